// Round 3
// baseline (872.610 us; speedup 1.0000x reference)
//
#include <hip/hip_runtime.h>
#include <math.h>

// Problem constants (B=1)
#define NH    12      // heads
#define NRES  768     // sequence length
#define C1V   384
#define C2V   128
#define NPROJ 1152    // 192+192+192+144+144+288
#define QKD   28      // 16 scalar + 12 point dims
#define FDIM  2112    // 192 + 3*96 + 96 + 1536
#define VVD   480     // 192 (v) + 288 (vp global)
#define APAD  772     // attn row pad
#define KSPLIT 11     // k5 split-K factor (2112 = 11 * 192)

typedef __attribute__((ext_vector_type(8))) short bf16x8;
typedef __attribute__((ext_vector_type(4))) float f32x4;

__device__ __forceinline__ float softplusf_(float x) {
    return (x > 20.f) ? x : log1pf(__expf(x));
}
__device__ __forceinline__ ushort f2bf(float x) {   // RNE f32 -> bf16
    union { float f; unsigned u; } v; v.f = x;
    unsigned r = (v.u + 0x7fffu + ((v.u >> 16) & 1u)) >> 16;
    return (ushort)r;
}

// ---------------------------------------------------------------------------
// K1: proj = act @ [wq|wk|wv|wqp|wkp|wvp] + [0|0|0|bqp|bkp|bvp]
//     block(0,0) additionally prepares w2dT (bf16 transposed w2d).
// ---------------------------------------------------------------------------
__global__ __launch_bounds__(256) void k1_proj(
    const float* __restrict__ act,
    const float* __restrict__ wq, const float* __restrict__ wk,
    const float* __restrict__ wv, const float* __restrict__ wqp,
    const float* __restrict__ wkp, const float* __restrict__ wvp,
    const float* __restrict__ bqp, const float* __restrict__ bkp,
    const float* __restrict__ bvp, const float* __restrict__ w2d,
    float* __restrict__ proj, ushort* __restrict__ w2dT)
{
    __shared__ float As[64 * 33];
    __shared__ float Bs[32 * 68];           // stride 68: float4-aligned B rows
    const int n0 = blockIdx.x * 64, m0 = blockIdx.y * 64;
    const int tid = threadIdx.x;
    const int tx = tid & 15, ty = tid >> 4;
    float c[4][4] = {};

    for (int kt = 0; kt < C1V; kt += 32) {
        for (int idx = tid; idx < 64 * 32; idx += 256) {
            int r = idx >> 5, j = idx & 31;
            As[r * 33 + j] = act[(m0 + r) * C1V + kt + j];
        }
        for (int idx = tid; idx < 32 * 64; idx += 256) {
            int r = idx >> 6, col = idx & 63;
            int jj = n0 + col, k = kt + r;
            float w;
            if      (jj < 192) w = wq [k * 192 + jj];
            else if (jj < 384) w = wk [k * 192 + jj - 192];
            else if (jj < 576) w = wv [k * 192 + jj - 384];
            else if (jj < 720) w = wqp[k * 144 + jj - 576];
            else if (jj < 864) w = wkp[k * 144 + jj - 720];
            else               w = wvp[k * 288 + jj - 864];
            Bs[r * 68 + col] = w;
        }
        __syncthreads();
        #pragma unroll
        for (int kk = 0; kk < 32; ++kk) {
            float a[4];
            #pragma unroll
            for (int i = 0; i < 4; ++i) a[i] = As[(ty * 4 + i) * 33 + kk];
            float4 b4 = *(const float4*)&Bs[kk * 68 + tx * 4];
            float b[4] = {b4.x, b4.y, b4.z, b4.w};
            #pragma unroll
            for (int i = 0; i < 4; ++i)
                #pragma unroll
                for (int j = 0; j < 4; ++j) c[i][j] += a[i] * b[j];
        }
        __syncthreads();
    }
    float biasv[4];
    #pragma unroll
    for (int j = 0; j < 4; ++j) {
        int col = n0 + tx * 4 + j;
        biasv[j] = (col >= 864) ? bvp[col - 864]
                 : (col >= 720) ? bkp[col - 720]
                 : (col >= 576) ? bqp[col - 576] : 0.f;
    }
    #pragma unroll
    for (int i = 0; i < 4; ++i) {
        float4 v;
        v.x = c[i][0] + biasv[0]; v.y = c[i][1] + biasv[1];
        v.z = c[i][2] + biasv[2]; v.w = c[i][3] + biasv[3];
        *(float4*)&proj[(m0 + ty * 4 + i) * NPROJ + n0 + tx * 4] = v;
    }
    // fold former kW_prep into block (0,0): w2dT[h][c] bf16, h padded to 16
    if (n0 == 0 && m0 == 0) {
        for (int idx = tid; idx < 2048; idx += 256) {
            int h = idx >> 7, cc = idx & 127;
            w2dT[idx] = (h < NH) ? f2bf(w2d[cc * NH + h]) : (ushort)0;
        }
    }
}

// ---------------------------------------------------------------------------
// K2: per-residue prep. Qv[n][h][28], Kv[n][h][28], ak[n][h], vv[n][480].
// ---------------------------------------------------------------------------
__global__ __launch_bounds__(64) void k2_prep(
    const float* __restrict__ proj, const float* __restrict__ rot,
    const float* __restrict__ trans, const float* __restrict__ tw,
    float* __restrict__ Qv, float* __restrict__ Kv,
    float* __restrict__ akArr, float* __restrict__ vv)
{
    const int n = blockIdx.x, tid = threadIdx.x;
    __shared__ float kp2[48];
    const float* pr = proj + n * NPROJ;
    float R[9], T[3];
    #pragma unroll
    for (int i = 0; i < 9; ++i) R[i] = rot[n * 9 + i];
    #pragma unroll
    for (int i = 0; i < 3; ++i) T[i] = trans[n * 3 + i];

    for (int idx = tid; idx < 192; idx += 64) {
        int h = idx >> 4, cc = idx & 15;
        Qv[(n * NH + h) * QKD + cc] = pr[idx] * 0.25f;          // sqrt(1/16)
        Kv[(n * NH + h) * QKD + cc] = pr[192 + idx];
        vv[n * VVD + idx] = pr[384 + idx];                      // v
    }
    if (tid < 48) {
        int h = tid >> 2, p = tid & 3;
        float pwh = 0.23570226039551584f * softplusf_(tw[h]);   // sqrt(2/36)*softplus
        float lx = pr[576 + h * 12 + p];
        float ly = pr[576 + h * 12 + 4 + p];
        float lz = pr[576 + h * 12 + 8 + p];
        float gx = R[0] * lx + R[1] * ly + R[2] * lz + T[0];
        float gy = R[3] * lx + R[4] * ly + R[5] * lz + T[1];
        float gz = R[6] * lx + R[7] * ly + R[8] * lz + T[2];
        float* qd = &Qv[(n * NH + h) * QKD + 16];
        qd[p] = pwh * gx; qd[4 + p] = pwh * gy; qd[8 + p] = pwh * gz;
        lx = pr[720 + h * 12 + p];
        ly = pr[720 + h * 12 + 4 + p];
        lz = pr[720 + h * 12 + 8 + p];
        gx = R[0] * lx + R[1] * ly + R[2] * lz + T[0];
        gy = R[3] * lx + R[4] * ly + R[5] * lz + T[1];
        gz = R[6] * lx + R[7] * ly + R[8] * lz + T[2];
        float* kd = &Kv[(n * NH + h) * QKD + 16];
        kd[p] = gx; kd[4 + p] = gy; kd[8 + p] = gz;
        kp2[tid] = gx * gx + gy * gy + gz * gz;
    }
    __syncthreads();
    if (tid < NH) {
        float pwh = 0.23570226039551584f * softplusf_(tw[tid]);
        akArr[n * NH + tid] = -0.5f * pwh *
            (kp2[tid * 4] + kp2[tid * 4 + 1] + kp2[tid * 4 + 2] + kp2[tid * 4 + 3]);
    }
    for (int idx = tid; idx < 96; idx += 64) {
        int h = idx >> 3, p = idx & 7;
        float lx = pr[864 + h * 24 + p];
        float ly = pr[864 + h * 24 + 8 + p];
        float lz = pr[864 + h * 24 + 16 + p];
        float gx = R[0] * lx + R[1] * ly + R[2] * lz + T[0];
        float gy = R[3] * lx + R[4] * ly + R[5] * lz + T[1];
        float gz = R[6] * lx + R[7] * ly + R[8] * lz + T[2];
        float* dst = &vv[n * VVD + 192 + h * 24 + p * 3];
        dst[0] = gx; dst[1] = gy; dst[2] = gz;
    }
}

// ---------------------------------------------------------------------------
// KA: fused logits. Per lane (h=nb<12, 4 k-rows): qk = Qv.Kv (K=28, L2-hot),
//     + ak[k,h], + act2d@w2d via bf16 MFMA, + mask, * sqrt(1/3).
//     qkBuf is now WRITE-ONLY (k2b eliminated).
// ---------------------------------------------------------------------------
__global__ __launch_bounds__(256) void kA_mfma(
    const float* __restrict__ act2d, const float* __restrict__ smask,
    const ushort* __restrict__ w2dT, const float* __restrict__ Qv,
    const float* __restrict__ Kv, const float* __restrict__ akArr,
    float* __restrict__ qkBuf)
{
    const int q = blockIdx.y, k0 = blockIdx.x * 64, tid = threadIdx.x;
    __shared__ ushort tile[64 * 136];    // 17.4 KB
    const int lane = tid & 63, wv = tid >> 6;
    const int nb = lane & 15, quad = lane >> 4;
    const int kb = k0 + wv * 16 + quad * 4;

    // B-frags (w2d), same for all waves: B[k=quad*8+j+32s][n=nb]
    bf16x8 bfr[4];
    #pragma unroll
    for (int s = 0; s < 4; ++s)
        bfr[s] = *(const bf16x8*)&w2dT[nb * 128 + quad * 8 + s * 32];

    // stage + convert act2d chunk
    const float* src = act2d + ((size_t)q * NRES + k0) * C2V;
    #pragma unroll
    for (int i = 0; i < 8; ++i) {
        int f = tid + i * 256;               // 2048 float4-chunks (64 rows x 32)
        int r = f >> 5, c4 = f & 31;
        float4 v = ((const float4*)src)[f];
        ushort4 o = { f2bf(v.x), f2bf(v.y), f2bf(v.z), f2bf(v.w) };
        *(ushort4*)&tile[r * 136 + c4 * 4] = o;
    }

    // qk dot (K=28) + ak while staging is in flight; Qv/Kv are L2-resident
    float qk[4] = {0.f, 0.f, 0.f, 0.f};
    float ak[4] = {0.f, 0.f, 0.f, 0.f};
    if (nb < NH) {
        const float* Qr = &Qv[((size_t)q * NH + nb) * QKD];
        float4 qv[7];
        #pragma unroll
        for (int j = 0; j < 7; ++j) qv[j] = *(const float4*)&Qr[j * 4];
        #pragma unroll
        for (int r = 0; r < 4; ++r) {
            const float* Kr = &Kv[((size_t)(kb + r) * NH + nb) * QKD];
            float s = 0.f;
            #pragma unroll
            for (int j = 0; j < 7; ++j) {
                float4 kv = *(const float4*)&Kr[j * 4];
                s += qv[j].x * kv.x + qv[j].y * kv.y
                   + qv[j].z * kv.z + qv[j].w * kv.w;
            }
            qk[r] = s;
            ak[r] = akArr[(size_t)(kb + r) * NH + nb];
        }
    }
    __syncthreads();

    f32x4 acc = {0.f, 0.f, 0.f, 0.f};
    #pragma unroll
    for (int s = 0; s < 4; ++s) {
        bf16x8 af = *(const bf16x8*)&tile[(wv * 16 + nb) * 136 + quad * 8 + s * 32];
        acc = __builtin_amdgcn_mfma_f32_16x16x32_bf16(af, bfr[s], acc, 0, 0, 0);
    }

    // epilogue: col = nb = h; rows = kb + reg   (write-only)
    if (nb < NH) {
        float4 sm = *(const float4*)&smask[kb];
        const float smq = smask[q];
        const float scale = 0.5773502691896258f;   // sqrt(1/3)
        float4 outv;
        outv.x = (qk[0] + ak[0] + acc[0] - 1e5f * (1.f - smq * sm.x)) * scale;
        outv.y = (qk[1] + ak[1] + acc[1] - 1e5f * (1.f - smq * sm.y)) * scale;
        outv.z = (qk[2] + ak[2] + acc[2] - 1e5f * (1.f - smq * sm.z)) * scale;
        outv.w = (qk[3] + ak[3] + acc[3] - 1e5f * (1.f - smq * sm.w)) * scale;
        *(float4*)&qkBuf[((size_t)(q * NH + nb)) * NRES + kb] = outv;
    }
}

// ---------------------------------------------------------------------------
// KC: per-q softmax + r2d (direct coalesced global act2d reads, no tile)
//     + vv pass.  LDS ~43.5 KB -> 3 blocks/CU.
//     Block 0 also zeroes the k5 split-K counters (stream-ordered before k5).
// ---------------------------------------------------------------------------
__global__ __launch_bounds__(256) void kC_attn(
    const float* __restrict__ act2d, const float* __restrict__ qkBuf,
    const float* __restrict__ vv, const float* __restrict__ rot,
    const float* __restrict__ trans, float* __restrict__ F,
    unsigned* __restrict__ cnt)
{
    const int q = blockIdx.x, tid = threadIdx.x;
    __shared__ float attnS[NH * APAD];     // 37.1 KB, unnormalized exp
    __shared__ float scr[1536];            // 6 KB scratch
    __shared__ float red[NH * 4];
    __shared__ float mh[NH], lh[NH];
    __shared__ float rotS[9], transS[3];

    if (q == 0 && tid < 72) cnt[tid] = 0u;
    if (tid < 9) rotS[tid] = rot[q * 9 + tid];
    if (tid < 3) transS[tid] = trans[q * 3 + tid];

    // ---- logits (masked+scaled by kA) ----
    float lg[3][NH];
    #pragma unroll
    for (int h = 0; h < NH; ++h)
        #pragma unroll
        for (int i = 0; i < 3; ++i)
            lg[i][h] = qkBuf[((size_t)(q * NH + h)) * NRES + tid + 256 * i];

    // ---- softmax over k ----
    const int wv_ = tid >> 6, lane = tid & 63;
    #pragma unroll
    for (int h = 0; h < NH; ++h) {
        float v = fmaxf(fmaxf(lg[0][h], lg[1][h]), lg[2][h]);
        for (int off = 32; off > 0; off >>= 1) v = fmaxf(v, __shfl_down(v, off, 64));
        if (lane == 0) red[h * 4 + wv_] = v;
    }
    __syncthreads();
    if (tid < NH)
        mh[tid] = fmaxf(fmaxf(red[tid * 4], red[tid * 4 + 1]),
                        fmaxf(red[tid * 4 + 2], red[tid * 4 + 3]));
    __syncthreads();
    float lsum[NH];
    #pragma unroll
    for (int h = 0; h < NH; ++h) lsum[h] = 0.f;
    #pragma unroll
    for (int i = 0; i < 3; ++i)
        #pragma unroll
        for (int h = 0; h < NH; ++h) {
            float e = __expf(lg[i][h] - mh[h]);
            attnS[h * APAD + tid + 256 * i] = e;
            lsum[h] += e;
        }
    #pragma unroll
    for (int h = 0; h < NH; ++h) {
        float v = lsum[h];
        for (int off = 32; off > 0; off >>= 1) v += __shfl_down(v, off, 64);
        if (lane == 0) red[h * 4 + wv_] = v;
    }
    __syncthreads();
    if (tid < NH)
        lh[tid] = 1.f / (red[tid * 4] + red[tid * 4 + 1] + red[tid * 4 + 2] + red[tid * 4 + 3]);
    __syncthreads();

    // ---- r2d: direct global streaming ----
    // thread = (cq 0..31, hg 0..3, kg 0..1): c = 4cq.., h = 3hg.., k-half kg
    const int cq = tid & 31, hg = (tid >> 5) & 3, kg = tid >> 7;
    const int h0 = 3 * hg;
    const float* abase = act2d + ((size_t)q * NRES + kg * 384) * C2V + cq * 4;
    const float* at0 = &attnS[(h0    ) * APAD + kg * 384];
    const float* at1 = &attnS[(h0 + 1) * APAD + kg * 384];
    const float* at2 = &attnS[(h0 + 2) * APAD + kg * 384];
    float4 a0 = {0,0,0,0}, a1 = {0,0,0,0}, a2 = {0,0,0,0};

    for (int kk = 0; kk < 384; kk += 4) {
        float4 t0 = *(const float4*)&abase[(size_t)(kk    ) * C2V];
        float4 t1 = *(const float4*)&abase[(size_t)(kk + 1) * C2V];
        float4 t2 = *(const float4*)&abase[(size_t)(kk + 2) * C2V];
        float4 t3 = *(const float4*)&abase[(size_t)(kk + 3) * C2V];
        float4 p0 = *(const float4*)&at0[kk];
        float4 p1 = *(const float4*)&at1[kk];
        float4 p2 = *(const float4*)&at2[kk];
        a0.x += p0.x*t0.x + p0.y*t1.x + p0.z*t2.x + p0.w*t3.x;
        a0.y += p0.x*t0.y + p0.y*t1.y + p0.z*t2.y + p0.w*t3.y;
        a0.z += p0.x*t0.z + p0.y*t1.z + p0.z*t2.z + p0.w*t3.z;
        a0.w += p0.x*t0.w + p0.y*t1.w + p0.z*t2.w + p0.w*t3.w;
        a1.x += p1.x*t0.x + p1.y*t1.x + p1.z*t2.x + p1.w*t3.x;
        a1.y += p1.x*t0.y + p1.y*t1.y + p1.z*t2.y + p1.w*t3.y;
        a1.z += p1.x*t0.z + p1.y*t1.z + p1.z*t2.z + p1.w*t3.z;
        a1.w += p1.x*t0.w + p1.y*t1.w + p1.z*t2.w + p1.w*t3.w;
        a2.x += p2.x*t0.x + p2.y*t1.x + p2.z*t2.x + p2.w*t3.x;
        a2.y += p2.x*t0.y + p2.y*t1.y + p2.z*t2.y + p2.w*t3.y;
        a2.z += p2.x*t0.z + p2.y*t1.z + p2.z*t2.z + p2.w*t3.z;
        a2.w += p2.x*t0.w + p2.y*t1.w + p2.z*t2.w + p2.w*t3.w;
    }
    if (kg == 1) {
        *(float4*)&scr[(h0    ) * 128 + cq * 4] = a0;
        *(float4*)&scr[(h0 + 1) * 128 + cq * 4] = a1;
        *(float4*)&scr[(h0 + 2) * 128 + cq * 4] = a2;
    }
    __syncthreads();
    float* Fq = F + q * FDIM;
    if (kg == 0) {
        float4 b0 = *(const float4*)&scr[(h0    ) * 128 + cq * 4];
        float4 b1 = *(const float4*)&scr[(h0 + 1) * 128 + cq * 4];
        float4 b2 = *(const float4*)&scr[(h0 + 2) * 128 + cq * 4];
        float l0 = lh[h0], l1 = lh[h0 + 1], l2 = lh[h0 + 2];
        float4 o0 = {(a0.x+b0.x)*l0, (a0.y+b0.y)*l0, (a0.z+b0.z)*l0, (a0.w+b0.w)*l0};
        float4 o1 = {(a1.x+b1.x)*l1, (a1.y+b1.y)*l1, (a1.z+b1.z)*l1, (a1.w+b1.w)*l1};
        float4 o2 = {(a2.x+b2.x)*l2, (a2.y+b2.y)*l2, (a2.z+b2.z)*l2, (a2.w+b2.w)*l2};
        *(float4*)&Fq[576 + (h0    ) * 128 + cq * 4] = o0;
        *(float4*)&Fq[576 + (h0 + 1) * 128 + cq * 4] = o1;
        *(float4*)&Fq[576 + (h0 + 2) * 128 + cq * 4] = o2;
    }
    __syncthreads();

    // ---- vv pass: out[j] = sum_k attn[hmap(j)][k] * vv[k][j], j in [0,480) ----
    const int j4 = tid & 127;                    // active if j4 < 120
    const int kgv = tid >> 7;
    float p0 = 0.f, p1 = 0.f, p2 = 0.f, p3 = 0.f;
    if (j4 < 120) {
        const int h = (j4 < 48) ? (j4 >> 2) : ((j4 - 48) / 6);
        const float* at = &attnS[h * APAD + kgv * 384];
        const float* col = vv + (size_t)(kgv * 384) * VVD + j4 * 4;
        #pragma unroll 8
        for (int k = 0; k < 384; ++k) {
            float a = at[k];
            float4 v = *(const float4*)(col + (size_t)k * VVD);
            p0 += a * v.x; p1 += a * v.y; p2 += a * v.z; p3 += a * v.w;
        }
    }
    __syncthreads();
    if (j4 < 120) {
        float4 pv = {p0, p1, p2, p3};
        *(float4*)&scr[(kgv * 120 + j4) * 4] = pv;
    }
    __syncthreads();
    if (tid < 120) {
        float4 a = *(const float4*)&scr[tid * 4];
        float4 b = *(const float4*)&scr[(120 + tid) * 4];
        const int h = (tid < 48) ? (tid >> 2) : ((tid - 48) / 6);
        const float il = lh[h];
        float4 s = {(a.x + b.x) * il, (a.y + b.y) * il,
                    (a.z + b.z) * il, (a.w + b.w) * il};
        if (tid < 48) {
            *(float4*)&Fq[tid * 4] = s;                 // res_scalar (192)
        } else {
            *(float4*)&scr[1024 + (tid - 48) * 4] = s;  // rpg (288)
        }
    }
    __syncthreads();
    if (tid < 96) {
        float gx = scr[1024 + tid * 3]     - transS[0];
        float gy = scr[1024 + tid * 3 + 1] - transS[1];
        float gz = scr[1024 + tid * 3 + 2] - transS[2];
        // invert_apply: rpl_i = sum_j R[j][i] * g_j
        float x = rotS[0] * gx + rotS[3] * gy + rotS[6] * gz;
        float y = rotS[1] * gx + rotS[4] * gy + rotS[7] * gz;
        float z = rotS[2] * gx + rotS[5] * gy + rotS[8] * gz;
        Fq[192 + tid] = x;
        Fq[288 + tid] = y;
        Fq[384 + tid] = z;
        Fq[480 + tid] = sqrtf(x * x + y * y + z * z);
    }
}

// ---------------------------------------------------------------------------
// K5: split-K partials; last block per (m,n) tile reduces + bias -> out.
// ---------------------------------------------------------------------------
__global__ __launch_bounds__(256) void k5_partial(
    const float* __restrict__ F, const float* __restrict__ wfin,
    const float* __restrict__ bfin, float* __restrict__ part,
    unsigned* __restrict__ cnt, float* __restrict__ out)
{
    const int n0 = blockIdx.x * 64, m0 = blockIdx.y * 64, kz = blockIdx.z;
    const int kbeg = kz * 192;
    __shared__ float As[64 * 33];
    __shared__ float Bs[32 * 68];           // stride 68: float4-aligned B rows
    const int tid = threadIdx.x, tx = tid & 15, ty = tid >> 4;
    float c[4][4] = {};

    for (int kt = kbeg; kt < kbeg + 192; kt += 32) {
        for (int idx = tid; idx < 64 * 32; idx += 256) {
            int r = idx >> 5, j = idx & 31;
            As[r * 33 + j] = F[(m0 + r) * FDIM + kt + j];
        }
        for (int idx = tid; idx < 32 * 64; idx += 256) {
            int r = idx >> 6, col = idx & 63;
            Bs[r * 68 + col] = wfin[(kt + r) * 384 + n0 + col];
        }
        __syncthreads();
        #pragma unroll
        for (int kk = 0; kk < 32; ++kk) {
            float a[4];
            #pragma unroll
            for (int i = 0; i < 4; ++i) a[i] = As[(ty * 4 + i) * 33 + kk];
            float4 b4 = *(const float4*)&Bs[kk * 68 + tx * 4];
            float b[4] = {b4.x, b4.y, b4.z, b4.w};
            #pragma unroll
            for (int i = 0; i < 4; ++i)
                #pragma unroll
                for (int j = 0; j < 4; ++j) c[i][j] += a[i] * b[j];
        }
        __syncthreads();
    }
    float* dst = part + (size_t)kz * (768 * 384);
    #pragma unroll
    for (int i = 0; i < 4; ++i) {
        float4 v = {c[i][0], c[i][1], c[i][2], c[i][3]};
        *(float4*)&dst[(m0 + ty * 4 + i) * 384 + n0 + tx * 4] = v;
    }

    // ---- split-K completion: last block for this (m,n) tile reduces ----
    __threadfence();                        // make partials visible device-wide
    __shared__ int isLast;
    if (tid == 0) {
        unsigned old = atomicAdd(&cnt[blockIdx.y * 6 + blockIdx.x], 1u);
        isLast = (old == KSPLIT - 1) ? 1 : 0;
    }
    __syncthreads();
    if (isLast) {
        __threadfence();                    // acquire: see other blocks' partials
        #pragma unroll
        for (int i = 0; i < 4; ++i) {
            const int row = m0 + ty * 4 + i, colb = n0 + tx * 4;
            float4 s = *(const float4*)&bfin[colb];
            #pragma unroll
            for (int kzz = 0; kzz < KSPLIT; ++kzz) {
                float4 v = *(const float4*)&part[(size_t)kzz * (768 * 384)
                                                 + (size_t)row * 384 + colb];
                s.x += v.x; s.y += v.y; s.z += v.z; s.w += v.w;
            }
            *(float4*)&out[(size_t)row * 384 + colb] = s;
        }
    }
}

// ---------------------------------------------------------------------------
extern "C" void kernel_launch(void* const* d_in, const int* in_sizes, int n_in,
                              void* d_out, int out_size, void* d_ws, size_t ws_size,
                              hipStream_t stream) {
    const float* act   = (const float*)d_in[0];
    const float* act2d = (const float*)d_in[1];
    const float* smask = (const float*)d_in[2];
    const float* rot   = (const float*)d_in[3];
    const float* trans = (const float*)d_in[4];
    const float* wq    = (const float*)d_in[5];
    const float* wk    = (const float*)d_in[6];
    const float* wvv   = (const float*)d_in[7];
    const float* wqp   = (const float*)d_in[8];
    const float* bqp   = (const float*)d_in[9];
    const float* wkp   = (const float*)d_in[10];
    const float* bkp   = (const float*)d_in[11];
    const float* wvp   = (const float*)d_in[12];
    const float* bvp   = (const float*)d_in[13];
    const float* w2d   = (const float*)d_in[14];
    // d_in[15] = b2d: constant over k, cancels in softmax over k -> unused
    const float* wfin  = (const float*)d_in[16];
    const float* bfin  = (const float*)d_in[17];
    const float* tw    = (const float*)d_in[18];

    float* W     = (float*)d_ws;
    float* proj  = W;                      // 768*1152
    float* Qv    = proj  + 768 * NPROJ;    // 768*12*28
    float* Kv    = Qv    + 768 * NH * QKD;
    float* akArr = Kv    + 768 * NH * QKD; // 768*12
    float* vvA   = akArr + 768 * NH;       // 768*480
    float* qkBuf = vvA   + 768 * VVD;      // 768*12*768 (7.08M floats)
    float* F     = qkBuf + 768 * NH * NRES;// 768*2112
    ushort* w2dT = (ushort*)(F + 768 * FDIM); // 2048 bf16
    unsigned* cnt = (unsigned*)(w2dT + 2048); // 72 split-K counters
    float* part  = qkBuf;                  // k5 partials alias qkBuf (dead by then)

    k1_proj<<<dim3(18, 12), 256, 0, stream>>>(act, wq, wk, wvv, wqp, wkp, wvp,
                                              bqp, bkp, bvp, w2d, proj, w2dT);
    k2_prep<<<dim3(NRES), 64, 0, stream>>>(proj, rot, trans, tw, Qv, Kv, akArr, vvA);
    kA_mfma<<<dim3(12, NRES), 256, 0, stream>>>(act2d, smask, w2dT, Qv, Kv, akArr,
                                                qkBuf);
    kC_attn<<<dim3(NRES), 256, 0, stream>>>(act2d, qkBuf, vvA, rot, trans, F, cnt);
    k5_partial<<<dim3(6, 12, KSPLIT), 256, 0, stream>>>(F, wfin, bfin, part, cnt,
                                                        (float*)d_out);
}

// Round 4
// 782.146 us; speedup vs baseline: 1.1157x; 1.1157x over previous
//
#include <hip/hip_runtime.h>
#include <math.h>

// Problem constants (B=1)
#define NH    12      // heads
#define NRES  768     // sequence length
#define C1V   384
#define C2V   128
#define NPROJ 1152    // 192+192+192+144+144+288
#define QKD   28      // 16 scalar + 12 point dims
#define FDIM  2112    // 192 + 3*96 + 96 + 1536
#define VVD   480     // 192 (v) + 288 (vp global)
#define APAD  772     // attn row pad
#define KSPLIT 11     // k5 split-K factor (2112 = 11 * 192)

typedef __attribute__((ext_vector_type(8))) short bf16x8;
typedef __attribute__((ext_vector_type(4))) float f32x4;

__device__ __forceinline__ float softplusf_(float x) {
    return (x > 20.f) ? x : log1pf(__expf(x));
}
__device__ __forceinline__ ushort f2bf(float x) {   // RNE f32 -> bf16
    union { float f; unsigned u; } v; v.f = x;
    unsigned r = (v.u + 0x7fffu + ((v.u >> 16) & 1u)) >> 16;
    return (ushort)r;
}

// ---------------------------------------------------------------------------
// K1: proj = act @ [wq|wk|wv|wqp|wkp|wvp] + [0|0|0|bqp|bkp|bvp]
//     block(0,0) additionally prepares w2dT (bf16 transposed w2d).
// ---------------------------------------------------------------------------
__global__ __launch_bounds__(256) void k1_proj(
    const float* __restrict__ act,
    const float* __restrict__ wq, const float* __restrict__ wk,
    const float* __restrict__ wv, const float* __restrict__ wqp,
    const float* __restrict__ wkp, const float* __restrict__ wvp,
    const float* __restrict__ bqp, const float* __restrict__ bkp,
    const float* __restrict__ bvp, const float* __restrict__ w2d,
    float* __restrict__ proj, ushort* __restrict__ w2dT)
{
    __shared__ float As[64 * 33];
    __shared__ float Bs[32 * 68];           // stride 68: float4-aligned B rows
    const int n0 = blockIdx.x * 64, m0 = blockIdx.y * 64;
    const int tid = threadIdx.x;
    const int tx = tid & 15, ty = tid >> 4;
    float c[4][4] = {};

    for (int kt = 0; kt < C1V; kt += 32) {
        for (int idx = tid; idx < 64 * 32; idx += 256) {
            int r = idx >> 5, j = idx & 31;
            As[r * 33 + j] = act[(m0 + r) * C1V + kt + j];
        }
        for (int idx = tid; idx < 32 * 64; idx += 256) {
            int r = idx >> 6, col = idx & 63;
            int jj = n0 + col, k = kt + r;
            float w;
            if      (jj < 192) w = wq [k * 192 + jj];
            else if (jj < 384) w = wk [k * 192 + jj - 192];
            else if (jj < 576) w = wv [k * 192 + jj - 384];
            else if (jj < 720) w = wqp[k * 144 + jj - 576];
            else if (jj < 864) w = wkp[k * 144 + jj - 720];
            else               w = wvp[k * 288 + jj - 864];
            Bs[r * 68 + col] = w;
        }
        __syncthreads();
        #pragma unroll
        for (int kk = 0; kk < 32; ++kk) {
            float a[4];
            #pragma unroll
            for (int i = 0; i < 4; ++i) a[i] = As[(ty * 4 + i) * 33 + kk];
            float4 b4 = *(const float4*)&Bs[kk * 68 + tx * 4];
            float b[4] = {b4.x, b4.y, b4.z, b4.w};
            #pragma unroll
            for (int i = 0; i < 4; ++i)
                #pragma unroll
                for (int j = 0; j < 4; ++j) c[i][j] += a[i] * b[j];
        }
        __syncthreads();
    }
    float biasv[4];
    #pragma unroll
    for (int j = 0; j < 4; ++j) {
        int col = n0 + tx * 4 + j;
        biasv[j] = (col >= 864) ? bvp[col - 864]
                 : (col >= 720) ? bkp[col - 720]
                 : (col >= 576) ? bqp[col - 576] : 0.f;
    }
    #pragma unroll
    for (int i = 0; i < 4; ++i) {
        float4 v;
        v.x = c[i][0] + biasv[0]; v.y = c[i][1] + biasv[1];
        v.z = c[i][2] + biasv[2]; v.w = c[i][3] + biasv[3];
        *(float4*)&proj[(m0 + ty * 4 + i) * NPROJ + n0 + tx * 4] = v;
    }
    // fold former kW_prep into block (0,0): w2dT[h][c] bf16, h padded to 16
    if (n0 == 0 && m0 == 0) {
        for (int idx = tid; idx < 2048; idx += 256) {
            int h = idx >> 7, cc = idx & 127;
            w2dT[idx] = (h < NH) ? f2bf(w2d[cc * NH + h]) : (ushort)0;
        }
    }
}

// ---------------------------------------------------------------------------
// K2: per-residue prep. Qv[n][h][28], Kv[n][h][28], ak[n][h], vv[n][480].
// ---------------------------------------------------------------------------
__global__ __launch_bounds__(64) void k2_prep(
    const float* __restrict__ proj, const float* __restrict__ rot,
    const float* __restrict__ trans, const float* __restrict__ tw,
    float* __restrict__ Qv, float* __restrict__ Kv,
    float* __restrict__ akArr, float* __restrict__ vv)
{
    const int n = blockIdx.x, tid = threadIdx.x;
    __shared__ float kp2[48];
    const float* pr = proj + n * NPROJ;
    float R[9], T[3];
    #pragma unroll
    for (int i = 0; i < 9; ++i) R[i] = rot[n * 9 + i];
    #pragma unroll
    for (int i = 0; i < 3; ++i) T[i] = trans[n * 3 + i];

    for (int idx = tid; idx < 192; idx += 64) {
        int h = idx >> 4, cc = idx & 15;
        Qv[(n * NH + h) * QKD + cc] = pr[idx] * 0.25f;          // sqrt(1/16)
        Kv[(n * NH + h) * QKD + cc] = pr[192 + idx];
        vv[n * VVD + idx] = pr[384 + idx];                      // v
    }
    if (tid < 48) {
        int h = tid >> 2, p = tid & 3;
        float pwh = 0.23570226039551584f * softplusf_(tw[h]);   // sqrt(2/36)*softplus
        float lx = pr[576 + h * 12 + p];
        float ly = pr[576 + h * 12 + 4 + p];
        float lz = pr[576 + h * 12 + 8 + p];
        float gx = R[0] * lx + R[1] * ly + R[2] * lz + T[0];
        float gy = R[3] * lx + R[4] * ly + R[5] * lz + T[1];
        float gz = R[6] * lx + R[7] * ly + R[8] * lz + T[2];
        float* qd = &Qv[(n * NH + h) * QKD + 16];
        qd[p] = pwh * gx; qd[4 + p] = pwh * gy; qd[8 + p] = pwh * gz;
        lx = pr[720 + h * 12 + p];
        ly = pr[720 + h * 12 + 4 + p];
        lz = pr[720 + h * 12 + 8 + p];
        gx = R[0] * lx + R[1] * ly + R[2] * lz + T[0];
        gy = R[3] * lx + R[4] * ly + R[5] * lz + T[1];
        gz = R[6] * lx + R[7] * ly + R[8] * lz + T[2];
        float* kd = &Kv[(n * NH + h) * QKD + 16];
        kd[p] = gx; kd[4 + p] = gy; kd[8 + p] = gz;
        kp2[tid] = gx * gx + gy * gy + gz * gz;
    }
    __syncthreads();
    if (tid < NH) {
        float pwh = 0.23570226039551584f * softplusf_(tw[tid]);
        akArr[n * NH + tid] = -0.5f * pwh *
            (kp2[tid * 4] + kp2[tid * 4 + 1] + kp2[tid * 4 + 2] + kp2[tid * 4 + 3]);
    }
    for (int idx = tid; idx < 96; idx += 64) {
        int h = idx >> 3, p = idx & 7;
        float lx = pr[864 + h * 24 + p];
        float ly = pr[864 + h * 24 + 8 + p];
        float lz = pr[864 + h * 24 + 16 + p];
        float gx = R[0] * lx + R[1] * ly + R[2] * lz + T[0];
        float gy = R[3] * lx + R[4] * ly + R[5] * lz + T[1];
        float gz = R[6] * lx + R[7] * ly + R[8] * lz + T[2];
        float* dst = &vv[n * VVD + 192 + h * 24 + p * 3];
        dst[0] = gx; dst[1] = gy; dst[2] = gz;
    }
}

// ---------------------------------------------------------------------------
// K2b: qkBuf[q][h][k] = Qv[q,h,:].Kv[k,h,:] + ak[k,h]   (raw, unmasked)
// ---------------------------------------------------------------------------
__global__ __launch_bounds__(256) void k2b_qk(
    const float* __restrict__ Qv, const float* __restrict__ Kv,
    const float* __restrict__ akArr, float* __restrict__ qkBuf)
{
    const int h = blockIdx.z;
    const int k0 = blockIdx.x * 64, q0 = blockIdx.y * 64;
    __shared__ float As[64 * 29];
    __shared__ float Bs[64 * 29];
    const int tid = threadIdx.x, tx = tid & 15, ty = tid >> 4;

    for (int idx = tid; idx < 64 * 28; idx += 256) {
        int r = idx / 28, j = idx - r * 28;
        As[r * 29 + j] = Qv[((q0 + r) * NH + h) * QKD + j];
        Bs[r * 29 + j] = Kv[((k0 + r) * NH + h) * QKD + j];
    }
    __syncthreads();
    float c[4][4] = {};
    #pragma unroll
    for (int kk = 0; kk < 28; ++kk) {
        float a[4], b[4];
        #pragma unroll
        for (int i = 0; i < 4; ++i) a[i] = As[(ty * 4 + i) * 29 + kk];
        #pragma unroll
        for (int j = 0; j < 4; ++j) b[j] = Bs[(tx * 4 + j) * 29 + kk];
        #pragma unroll
        for (int i = 0; i < 4; ++i)
            #pragma unroll
            for (int j = 0; j < 4; ++j) c[i][j] += a[i] * b[j];
    }
    float akv[4];
    #pragma unroll
    for (int j = 0; j < 4; ++j) akv[j] = akArr[(k0 + tx * 4 + j) * NH + h];
    #pragma unroll
    for (int i = 0; i < 4; ++i) {
        float4 v;
        v.x = c[i][0] + akv[0]; v.y = c[i][1] + akv[1];
        v.z = c[i][2] + akv[2]; v.w = c[i][3] + akv[3];
        *(float4*)&qkBuf[((q0 + ty * 4 + i) * NH + h) * NRES + k0 + tx * 4] = v;
    }
}

// ---------------------------------------------------------------------------
// KA: logits += act2d @ w2d via bf16 MFMA.  grid (12 ktiles, 768 q).
//   NO LDS, NO barrier: each lane loads its A-fragment directly from global
//   (8 independent float4 loads), converts to bf16 in-register, 4 MFMAs,
//   then masked RMW epilogue on qkBuf.  Pure-streaming, latency hidden by
//   occupancy (no LDS -> blocks limited only by VGPRs).
// ---------------------------------------------------------------------------
__global__ __launch_bounds__(256) void kA_mfma(
    const float* __restrict__ act2d, const float* __restrict__ smask,
    const ushort* __restrict__ w2dT, float* __restrict__ qkBuf)
{
    const int q = blockIdx.y, k0 = blockIdx.x * 64, tid = threadIdx.x;
    const int lane = tid & 63, wv = tid >> 6;
    const int nb = lane & 15, quad = lane >> 4;

    // B-frags (w2d): B[kc=quad*8+j+32s][n=nb]
    bf16x8 bfr[4];
    #pragma unroll
    for (int s = 0; s < 4; ++s)
        bfr[s] = *(const bf16x8*)&w2dT[nb * 128 + quad * 8 + s * 32];

    // A-frags direct from global: row = k0+wv*16+nb, cols quad*8+s*32..+7
    const int krow = k0 + wv * 16 + nb;
    const float* arow = act2d + ((size_t)q * NRES + krow) * C2V + quad * 8;
    float4 u[4], w[4];
    #pragma unroll
    for (int s = 0; s < 4; ++s) {
        u[s] = *(const float4*)&arow[s * 32];
        w[s] = *(const float4*)&arow[s * 32 + 4];
    }
    f32x4 acc = {0.f, 0.f, 0.f, 0.f};
    #pragma unroll
    for (int s = 0; s < 4; ++s) {
        bf16x8 af;
        af[0] = (short)f2bf(u[s].x); af[1] = (short)f2bf(u[s].y);
        af[2] = (short)f2bf(u[s].z); af[3] = (short)f2bf(u[s].w);
        af[4] = (short)f2bf(w[s].x); af[5] = (short)f2bf(w[s].y);
        af[6] = (short)f2bf(w[s].z); af[7] = (short)f2bf(w[s].w);
        acc = __builtin_amdgcn_mfma_f32_16x16x32_bf16(af, bfr[s], acc, 0, 0, 0);
    }

    // epilogue: col = nb = h; rows = k0 + wv*16 + quad*4 + reg
    if (nb < NH) {
        const int kb = k0 + wv * 16 + quad * 4;
        float* dst = &qkBuf[((size_t)(q * NH + nb)) * NRES + kb];
        float4 old = *(float4*)dst;
        float4 sm = *(const float4*)&smask[kb];
        const float smq = smask[q];
        const float scale = 0.5773502691896258f;   // sqrt(1/3)
        float4 outv;
        outv.x = (old.x + acc[0] - 1e5f * (1.f - smq * sm.x)) * scale;
        outv.y = (old.y + acc[1] - 1e5f * (1.f - smq * sm.y)) * scale;
        outv.z = (old.z + acc[2] - 1e5f * (1.f - smq * sm.z)) * scale;
        outv.w = (old.w + acc[3] - 1e5f * (1.f - smq * sm.w)) * scale;
        *(float4*)dst = outv;
    }
}

// ---------------------------------------------------------------------------
// KC: per-q softmax + r2d (direct coalesced global act2d reads, no tile)
//     + vv pass.  LDS ~43.5 KB -> 3 blocks/CU.
//     Block 0 also zeroes the k5 split-K counters (stream-ordered before k5).
// ---------------------------------------------------------------------------
__global__ __launch_bounds__(256) void kC_attn(
    const float* __restrict__ act2d, const float* __restrict__ qkBuf,
    const float* __restrict__ vv, const float* __restrict__ rot,
    const float* __restrict__ trans, float* __restrict__ F,
    unsigned* __restrict__ cnt)
{
    const int q = blockIdx.x, tid = threadIdx.x;
    __shared__ float attnS[NH * APAD];     // 37.1 KB, unnormalized exp
    __shared__ float scr[1536];            // 6 KB scratch
    __shared__ float red[NH * 4];
    __shared__ float mh[NH], lh[NH];
    __shared__ float rotS[9], transS[3];

    if (q == 0 && tid < 72) cnt[tid] = 0u;
    if (tid < 9) rotS[tid] = rot[q * 9 + tid];
    if (tid < 3) transS[tid] = trans[q * 3 + tid];

    // ---- logits (masked+scaled by kA) ----
    float lg[3][NH];
    #pragma unroll
    for (int h = 0; h < NH; ++h)
        #pragma unroll
        for (int i = 0; i < 3; ++i)
            lg[i][h] = qkBuf[((size_t)(q * NH + h)) * NRES + tid + 256 * i];

    // ---- softmax over k ----
    const int wv_ = tid >> 6, lane = tid & 63;
    #pragma unroll
    for (int h = 0; h < NH; ++h) {
        float v = fmaxf(fmaxf(lg[0][h], lg[1][h]), lg[2][h]);
        for (int off = 32; off > 0; off >>= 1) v = fmaxf(v, __shfl_down(v, off, 64));
        if (lane == 0) red[h * 4 + wv_] = v;
    }
    __syncthreads();
    if (tid < NH)
        mh[tid] = fmaxf(fmaxf(red[tid * 4], red[tid * 4 + 1]),
                        fmaxf(red[tid * 4 + 2], red[tid * 4 + 3]));
    __syncthreads();
    float lsum[NH];
    #pragma unroll
    for (int h = 0; h < NH; ++h) lsum[h] = 0.f;
    #pragma unroll
    for (int i = 0; i < 3; ++i)
        #pragma unroll
        for (int h = 0; h < NH; ++h) {
            float e = __expf(lg[i][h] - mh[h]);
            attnS[h * APAD + tid + 256 * i] = e;
            lsum[h] += e;
        }
    #pragma unroll
    for (int h = 0; h < NH; ++h) {
        float v = lsum[h];
        for (int off = 32; off > 0; off >>= 1) v += __shfl_down(v, off, 64);
        if (lane == 0) red[h * 4 + wv_] = v;
    }
    __syncthreads();
    if (tid < NH)
        lh[tid] = 1.f / (red[tid * 4] + red[tid * 4 + 1] + red[tid * 4 + 2] + red[tid * 4 + 3]);
    __syncthreads();

    // ---- r2d: direct global streaming ----
    // thread = (cq 0..31, hg 0..3, kg 0..1): c = 4cq.., h = 3hg.., k-half kg
    const int cq = tid & 31, hg = (tid >> 5) & 3, kg = tid >> 7;
    const int h0 = 3 * hg;
    const float* abase = act2d + ((size_t)q * NRES + kg * 384) * C2V + cq * 4;
    const float* at0 = &attnS[(h0    ) * APAD + kg * 384];
    const float* at1 = &attnS[(h0 + 1) * APAD + kg * 384];
    const float* at2 = &attnS[(h0 + 2) * APAD + kg * 384];
    float4 a0 = {0,0,0,0}, a1 = {0,0,0,0}, a2 = {0,0,0,0};

    for (int kk = 0; kk < 384; kk += 4) {
        float4 t0 = *(const float4*)&abase[(size_t)(kk    ) * C2V];
        float4 t1 = *(const float4*)&abase[(size_t)(kk + 1) * C2V];
        float4 t2 = *(const float4*)&abase[(size_t)(kk + 2) * C2V];
        float4 t3 = *(const float4*)&abase[(size_t)(kk + 3) * C2V];
        float4 p0 = *(const float4*)&at0[kk];
        float4 p1 = *(const float4*)&at1[kk];
        float4 p2 = *(const float4*)&at2[kk];
        a0.x += p0.x*t0.x + p0.y*t1.x + p0.z*t2.x + p0.w*t3.x;
        a0.y += p0.x*t0.y + p0.y*t1.y + p0.z*t2.y + p0.w*t3.y;
        a0.z += p0.x*t0.z + p0.y*t1.z + p0.z*t2.z + p0.w*t3.z;
        a0.w += p0.x*t0.w + p0.y*t1.w + p0.z*t2.w + p0.w*t3.w;
        a1.x += p1.x*t0.x + p1.y*t1.x + p1.z*t2.x + p1.w*t3.x;
        a1.y += p1.x*t0.y + p1.y*t1.y + p1.z*t2.y + p1.w*t3.y;
        a1.z += p1.x*t0.z + p1.y*t1.z + p1.z*t2.z + p1.w*t3.z;
        a1.w += p1.x*t0.w + p1.y*t1.w + p1.z*t2.w + p1.w*t3.w;
        a2.x += p2.x*t0.x + p2.y*t1.x + p2.z*t2.x + p2.w*t3.x;
        a2.y += p2.x*t0.y + p2.y*t1.y + p2.z*t2.y + p2.w*t3.y;
        a2.z += p2.x*t0.z + p2.y*t1.z + p2.z*t2.z + p2.w*t3.z;
        a2.w += p2.x*t0.w + p2.y*t1.w + p2.z*t2.w + p2.w*t3.w;
    }
    if (kg == 1) {
        *(float4*)&scr[(h0    ) * 128 + cq * 4] = a0;
        *(float4*)&scr[(h0 + 1) * 128 + cq * 4] = a1;
        *(float4*)&scr[(h0 + 2) * 128 + cq * 4] = a2;
    }
    __syncthreads();
    float* Fq = F + q * FDIM;
    if (kg == 0) {
        float4 b0 = *(const float4*)&scr[(h0    ) * 128 + cq * 4];
        float4 b1 = *(const float4*)&scr[(h0 + 1) * 128 + cq * 4];
        float4 b2 = *(const float4*)&scr[(h0 + 2) * 128 + cq * 4];
        float l0 = lh[h0], l1 = lh[h0 + 1], l2 = lh[h0 + 2];
        float4 o0 = {(a0.x+b0.x)*l0, (a0.y+b0.y)*l0, (a0.z+b0.z)*l0, (a0.w+b0.w)*l0};
        float4 o1 = {(a1.x+b1.x)*l1, (a1.y+b1.y)*l1, (a1.z+b1.z)*l1, (a1.w+b1.w)*l1};
        float4 o2 = {(a2.x+b2.x)*l2, (a2.y+b2.y)*l2, (a2.z+b2.z)*l2, (a2.w+b2.w)*l2};
        *(float4*)&Fq[576 + (h0    ) * 128 + cq * 4] = o0;
        *(float4*)&Fq[576 + (h0 + 1) * 128 + cq * 4] = o1;
        *(float4*)&Fq[576 + (h0 + 2) * 128 + cq * 4] = o2;
    }
    __syncthreads();

    // ---- vv pass: out[j] = sum_k attn[hmap(j)][k] * vv[k][j], j in [0,480) ----
    const int j4 = tid & 127;                    // active if j4 < 120
    const int kgv = tid >> 7;
    float p0 = 0.f, p1 = 0.f, p2 = 0.f, p3 = 0.f;
    if (j4 < 120) {
        const int h = (j4 < 48) ? (j4 >> 2) : ((j4 - 48) / 6);
        const float* at = &attnS[h * APAD + kgv * 384];
        const float* col = vv + (size_t)(kgv * 384) * VVD + j4 * 4;
        #pragma unroll 8
        for (int k = 0; k < 384; ++k) {
            float a = at[k];
            float4 v = *(const float4*)(col + (size_t)k * VVD);
            p0 += a * v.x; p1 += a * v.y; p2 += a * v.z; p3 += a * v.w;
        }
    }
    __syncthreads();
    if (j4 < 120) {
        float4 pv = {p0, p1, p2, p3};
        *(float4*)&scr[(kgv * 120 + j4) * 4] = pv;
    }
    __syncthreads();
    if (tid < 120) {
        float4 a = *(const float4*)&scr[tid * 4];
        float4 b = *(const float4*)&scr[(120 + tid) * 4];
        const int h = (tid < 48) ? (tid >> 2) : ((tid - 48) / 6);
        const float il = lh[h];
        float4 s = {(a.x + b.x) * il, (a.y + b.y) * il,
                    (a.z + b.z) * il, (a.w + b.w) * il};
        if (tid < 48) {
            *(float4*)&Fq[tid * 4] = s;                 // res_scalar (192)
        } else {
            *(float4*)&scr[1024 + (tid - 48) * 4] = s;  // rpg (288)
        }
    }
    __syncthreads();
    if (tid < 96) {
        float gx = scr[1024 + tid * 3]     - transS[0];
        float gy = scr[1024 + tid * 3 + 1] - transS[1];
        float gz = scr[1024 + tid * 3 + 2] - transS[2];
        // invert_apply: rpl_i = sum_j R[j][i] * g_j
        float x = rotS[0] * gx + rotS[3] * gy + rotS[6] * gz;
        float y = rotS[1] * gx + rotS[4] * gy + rotS[7] * gz;
        float z = rotS[2] * gx + rotS[5] * gy + rotS[8] * gz;
        Fq[192 + tid] = x;
        Fq[288 + tid] = y;
        Fq[384 + tid] = z;
        Fq[480 + tid] = sqrtf(x * x + y * y + z * z);
    }
}

// ---------------------------------------------------------------------------
// K5: split-K partials; last block per (m,n) tile reduces + bias -> out.
// ---------------------------------------------------------------------------
__global__ __launch_bounds__(256) void k5_partial(
    const float* __restrict__ F, const float* __restrict__ wfin,
    const float* __restrict__ bfin, float* __restrict__ part,
    unsigned* __restrict__ cnt, float* __restrict__ out)
{
    const int n0 = blockIdx.x * 64, m0 = blockIdx.y * 64, kz = blockIdx.z;
    const int kbeg = kz * 192;
    __shared__ float As[64 * 33];
    __shared__ float Bs[32 * 68];           // stride 68: float4-aligned B rows
    const int tid = threadIdx.x, tx = tid & 15, ty = tid >> 4;
    float c[4][4] = {};

    for (int kt = kbeg; kt < kbeg + 192; kt += 32) {
        for (int idx = tid; idx < 64 * 32; idx += 256) {
            int r = idx >> 5, j = idx & 31;
            As[r * 33 + j] = F[(m0 + r) * FDIM + kt + j];
        }
        for (int idx = tid; idx < 32 * 64; idx += 256) {
            int r = idx >> 6, col = idx & 63;
            Bs[r * 68 + col] = wfin[(kt + r) * 384 + n0 + col];
        }
        __syncthreads();
        #pragma unroll
        for (int kk = 0; kk < 32; ++kk) {
            float a[4];
            #pragma unroll
            for (int i = 0; i < 4; ++i) a[i] = As[(ty * 4 + i) * 33 + kk];
            float4 b4 = *(const float4*)&Bs[kk * 68 + tx * 4];
            float b[4] = {b4.x, b4.y, b4.z, b4.w};
            #pragma unroll
            for (int i = 0; i < 4; ++i)
                #pragma unroll
                for (int j = 0; j < 4; ++j) c[i][j] += a[i] * b[j];
        }
        __syncthreads();
    }
    float* dst = part + (size_t)kz * (768 * 384);
    #pragma unroll
    for (int i = 0; i < 4; ++i) {
        float4 v = {c[i][0], c[i][1], c[i][2], c[i][3]};
        *(float4*)&dst[(m0 + ty * 4 + i) * 384 + n0 + tx * 4] = v;
    }

    // ---- split-K completion: last block for this (m,n) tile reduces ----
    __threadfence();                        // make partials visible device-wide
    __shared__ int isLast;
    if (tid == 0) {
        unsigned old = atomicAdd(&cnt[blockIdx.y * 6 + blockIdx.x], 1u);
        isLast = (old == KSPLIT - 1) ? 1 : 0;
    }
    __syncthreads();
    if (isLast) {
        __threadfence();                    // acquire: see other blocks' partials
        #pragma unroll
        for (int i = 0; i < 4; ++i) {
            const int row = m0 + ty * 4 + i, colb = n0 + tx * 4;
            float4 s = *(const float4*)&bfin[colb];
            #pragma unroll
            for (int kzz = 0; kzz < KSPLIT; ++kzz) {
                float4 v = *(const float4*)&part[(size_t)kzz * (768 * 384)
                                                 + (size_t)row * 384 + colb];
                s.x += v.x; s.y += v.y; s.z += v.z; s.w += v.w;
            }
            *(float4*)&out[(size_t)row * 384 + colb] = s;
        }
    }
}

// ---------------------------------------------------------------------------
extern "C" void kernel_launch(void* const* d_in, const int* in_sizes, int n_in,
                              void* d_out, int out_size, void* d_ws, size_t ws_size,
                              hipStream_t stream) {
    const float* act   = (const float*)d_in[0];
    const float* act2d = (const float*)d_in[1];
    const float* smask = (const float*)d_in[2];
    const float* rot   = (const float*)d_in[3];
    const float* trans = (const float*)d_in[4];
    const float* wq    = (const float*)d_in[5];
    const float* wk    = (const float*)d_in[6];
    const float* wvv   = (const float*)d_in[7];
    const float* wqp   = (const float*)d_in[8];
    const float* bqp   = (const float*)d_in[9];
    const float* wkp   = (const float*)d_in[10];
    const float* bkp   = (const float*)d_in[11];
    const float* wvp   = (const float*)d_in[12];
    const float* bvp   = (const float*)d_in[13];
    const float* w2d   = (const float*)d_in[14];
    // d_in[15] = b2d: constant over k, cancels in softmax over k -> unused
    const float* wfin  = (const float*)d_in[16];
    const float* bfin  = (const float*)d_in[17];
    const float* tw    = (const float*)d_in[18];

    float* W     = (float*)d_ws;
    float* proj  = W;                      // 768*1152
    float* Qv    = proj  + 768 * NPROJ;    // 768*12*28
    float* Kv    = Qv    + 768 * NH * QKD;
    float* akArr = Kv    + 768 * NH * QKD; // 768*12
    float* vvA   = akArr + 768 * NH;       // 768*480
    float* qkBuf = vvA   + 768 * VVD;      // 768*12*768 (7.08M floats)
    float* F     = qkBuf + 768 * NH * NRES;// 768*2112
    ushort* w2dT = (ushort*)(F + 768 * FDIM); // 2048 bf16
    unsigned* cnt = (unsigned*)(w2dT + 2048); // 72 split-K counters
    float* part  = qkBuf;                  // k5 partials alias qkBuf (dead by then)

    k1_proj<<<dim3(18, 12), 256, 0, stream>>>(act, wq, wk, wvv, wqp, wkp, wvp,
                                              bqp, bkp, bvp, w2d, proj, w2dT);
    k2_prep<<<dim3(NRES), 64, 0, stream>>>(proj, rot, trans, tw, Qv, Kv, akArr, vvA);
    k2b_qk<<<dim3(12, 12, NH), 256, 0, stream>>>(Qv, Kv, akArr, qkBuf);
    kA_mfma<<<dim3(12, NRES), 256, 0, stream>>>(act2d, smask, w2dT, qkBuf);
    kC_attn<<<dim3(NRES), 256, 0, stream>>>(act2d, qkBuf, vvA, rot, trans, F, cnt);
    k5_partial<<<dim3(6, 12, KSPLIT), 256, 0, stream>>>(F, wfin, bfin, part, cnt,
                                                        (float*)d_out);
}

// Round 5
// 723.393 us; speedup vs baseline: 1.2063x; 1.0812x over previous
//
#include <hip/hip_runtime.h>
#include <math.h>

// Problem constants (B=1)
#define NH    12      // heads
#define NRES  768     // sequence length
#define C1V   384
#define C2V   128
#define NPROJ 1152    // 192+192+192+144+144+288
#define QKD   28      // 16 scalar + 12 point dims
#define FDIM  2112    // 192 + 3*96 + 96 + 1536
#define VVD   480     // 192 (v) + 288 (vp global)
#define KSPLIT 11     // k5 split-K factor (2112 = 11 * 192)
#define PSTR  2048    // per-(q,chunk) partial stride (floats)

typedef __attribute__((ext_vector_type(8))) short bf16x8;
typedef __attribute__((ext_vector_type(4))) float f32x4;

__device__ __forceinline__ float softplusf_(float x) {
    return (x > 20.f) ? x : log1pf(__expf(x));
}
__device__ __forceinline__ ushort f2bf(float x) {   // RNE f32 -> bf16
    union { float f; unsigned u; } v; v.f = x;
    unsigned r = (v.u + 0x7fffu + ((v.u >> 16) & 1u)) >> 16;
    return (ushort)r;
}

// ---------------------------------------------------------------------------
// K1: proj = act @ [wq|wk|wv|wqp|wkp|wvp] + [0|0|0|bqp|bkp|bvp]
//     block(0,0) additionally prepares w2dT (bf16 transposed w2d).
// ---------------------------------------------------------------------------
__global__ __launch_bounds__(256) void k1_proj(
    const float* __restrict__ act,
    const float* __restrict__ wq, const float* __restrict__ wk,
    const float* __restrict__ wv, const float* __restrict__ wqp,
    const float* __restrict__ wkp, const float* __restrict__ wvp,
    const float* __restrict__ bqp, const float* __restrict__ bkp,
    const float* __restrict__ bvp, const float* __restrict__ w2d,
    float* __restrict__ proj, ushort* __restrict__ w2dT)
{
    __shared__ float As[64 * 33];
    __shared__ float Bs[32 * 68];
    const int n0 = blockIdx.x * 64, m0 = blockIdx.y * 64;
    const int tid = threadIdx.x;
    const int tx = tid & 15, ty = tid >> 4;
    float c[4][4] = {};

    for (int kt = 0; kt < C1V; kt += 32) {
        for (int idx = tid; idx < 64 * 32; idx += 256) {
            int r = idx >> 5, j = idx & 31;
            As[r * 33 + j] = act[(m0 + r) * C1V + kt + j];
        }
        for (int idx = tid; idx < 32 * 64; idx += 256) {
            int r = idx >> 6, col = idx & 63;
            int jj = n0 + col, k = kt + r;
            float w;
            if      (jj < 192) w = wq [k * 192 + jj];
            else if (jj < 384) w = wk [k * 192 + jj - 192];
            else if (jj < 576) w = wv [k * 192 + jj - 384];
            else if (jj < 720) w = wqp[k * 144 + jj - 576];
            else if (jj < 864) w = wkp[k * 144 + jj - 720];
            else               w = wvp[k * 288 + jj - 864];
            Bs[r * 68 + col] = w;
        }
        __syncthreads();
        #pragma unroll
        for (int kk = 0; kk < 32; ++kk) {
            float a[4];
            #pragma unroll
            for (int i = 0; i < 4; ++i) a[i] = As[(ty * 4 + i) * 33 + kk];
            float4 b4 = *(const float4*)&Bs[kk * 68 + tx * 4];
            float b[4] = {b4.x, b4.y, b4.z, b4.w};
            #pragma unroll
            for (int i = 0; i < 4; ++i)
                #pragma unroll
                for (int j = 0; j < 4; ++j) c[i][j] += a[i] * b[j];
        }
        __syncthreads();
    }
    float biasv[4];
    #pragma unroll
    for (int j = 0; j < 4; ++j) {
        int col = n0 + tx * 4 + j;
        biasv[j] = (col >= 864) ? bvp[col - 864]
                 : (col >= 720) ? bkp[col - 720]
                 : (col >= 576) ? bqp[col - 576] : 0.f;
    }
    #pragma unroll
    for (int i = 0; i < 4; ++i) {
        float4 v;
        v.x = c[i][0] + biasv[0]; v.y = c[i][1] + biasv[1];
        v.z = c[i][2] + biasv[2]; v.w = c[i][3] + biasv[3];
        *(float4*)&proj[(m0 + ty * 4 + i) * NPROJ + n0 + tx * 4] = v;
    }
    if (n0 == 0 && m0 == 0) {
        for (int idx = tid; idx < 2048; idx += 256) {
            int h = idx >> 7, cc = idx & 127;
            w2dT[idx] = (h < NH) ? f2bf(w2d[cc * NH + h]) : (ushort)0;
        }
    }
}

// ---------------------------------------------------------------------------
// K2: per-residue prep. Qv[n][h][28], Kv[n][h][28], ak[n][h], vv[n][480].
// ---------------------------------------------------------------------------
__global__ __launch_bounds__(64) void k2_prep(
    const float* __restrict__ proj, const float* __restrict__ rot,
    const float* __restrict__ trans, const float* __restrict__ tw,
    float* __restrict__ Qv, float* __restrict__ Kv,
    float* __restrict__ akArr, float* __restrict__ vv)
{
    const int n = blockIdx.x, tid = threadIdx.x;
    __shared__ float kp2[48];
    const float* pr = proj + n * NPROJ;
    float R[9], T[3];
    #pragma unroll
    for (int i = 0; i < 9; ++i) R[i] = rot[n * 9 + i];
    #pragma unroll
    for (int i = 0; i < 3; ++i) T[i] = trans[n * 3 + i];

    for (int idx = tid; idx < 192; idx += 64) {
        int h = idx >> 4, cc = idx & 15;
        Qv[(n * NH + h) * QKD + cc] = pr[idx] * 0.25f;
        Kv[(n * NH + h) * QKD + cc] = pr[192 + idx];
        vv[n * VVD + idx] = pr[384 + idx];
    }
    if (tid < 48) {
        int h = tid >> 2, p = tid & 3;
        float pwh = 0.23570226039551584f * softplusf_(tw[h]);
        float lx = pr[576 + h * 12 + p];
        float ly = pr[576 + h * 12 + 4 + p];
        float lz = pr[576 + h * 12 + 8 + p];
        float gx = R[0] * lx + R[1] * ly + R[2] * lz + T[0];
        float gy = R[3] * lx + R[4] * ly + R[5] * lz + T[1];
        float gz = R[6] * lx + R[7] * ly + R[8] * lz + T[2];
        float* qd = &Qv[(n * NH + h) * QKD + 16];
        qd[p] = pwh * gx; qd[4 + p] = pwh * gy; qd[8 + p] = pwh * gz;
        lx = pr[720 + h * 12 + p];
        ly = pr[720 + h * 12 + 4 + p];
        lz = pr[720 + h * 12 + 8 + p];
        gx = R[0] * lx + R[1] * ly + R[2] * lz + T[0];
        gy = R[3] * lx + R[4] * ly + R[5] * lz + T[1];
        gz = R[6] * lx + R[7] * ly + R[8] * lz + T[2];
        float* kd = &Kv[(n * NH + h) * QKD + 16];
        kd[p] = gx; kd[4 + p] = gy; kd[8 + p] = gz;
        kp2[tid] = gx * gx + gy * gy + gz * gz;
    }
    __syncthreads();
    if (tid < NH) {
        float pwh = 0.23570226039551584f * softplusf_(tw[tid]);
        akArr[n * NH + tid] = -0.5f * pwh *
            (kp2[tid * 4] + kp2[tid * 4 + 1] + kp2[tid * 4 + 2] + kp2[tid * 4 + 3]);
    }
    for (int idx = tid; idx < 96; idx += 64) {
        int h = idx >> 3, p = idx & 7;
        float lx = pr[864 + h * 24 + p];
        float ly = pr[864 + h * 24 + 8 + p];
        float lz = pr[864 + h * 24 + 16 + p];
        float gx = R[0] * lx + R[1] * ly + R[2] * lz + T[0];
        float gy = R[3] * lx + R[4] * ly + R[5] * lz + T[1];
        float gz = R[6] * lx + R[7] * ly + R[8] * lz + T[2];
        float* dst = &vv[n * VVD + 192 + h * 24 + p * 3];
        dst[0] = gx; dst[1] = gy; dst[2] = gz;
    }
}

// ---------------------------------------------------------------------------
// K2b: qkBuf[q][h][k] = Qv[q,h,:].Kv[k,h,:] + ak[k,h]   (raw, unmasked)
// ---------------------------------------------------------------------------
__global__ __launch_bounds__(256) void k2b_qk(
    const float* __restrict__ Qv, const float* __restrict__ Kv,
    const float* __restrict__ akArr, float* __restrict__ qkBuf)
{
    const int h = blockIdx.z;
    const int k0 = blockIdx.x * 64, q0 = blockIdx.y * 64;
    __shared__ float As[64 * 29];
    __shared__ float Bs[64 * 29];
    const int tid = threadIdx.x, tx = tid & 15, ty = tid >> 4;

    for (int idx = tid; idx < 64 * 28; idx += 256) {
        int r = idx / 28, j = idx - r * 28;
        As[r * 29 + j] = Qv[((q0 + r) * NH + h) * QKD + j];
        Bs[r * 29 + j] = Kv[((k0 + r) * NH + h) * QKD + j];
    }
    __syncthreads();
    float c[4][4] = {};
    #pragma unroll
    for (int kk = 0; kk < 28; ++kk) {
        float a[4], b[4];
        #pragma unroll
        for (int i = 0; i < 4; ++i) a[i] = As[(ty * 4 + i) * 29 + kk];
        #pragma unroll
        for (int j = 0; j < 4; ++j) b[j] = Bs[(tx * 4 + j) * 29 + kk];
        #pragma unroll
        for (int i = 0; i < 4; ++i)
            #pragma unroll
            for (int j = 0; j < 4; ++j) c[i][j] += a[i] * b[j];
    }
    float akv[4];
    #pragma unroll
    for (int j = 0; j < 4; ++j) akv[j] = akArr[(k0 + tx * 4 + j) * NH + h];
    #pragma unroll
    for (int i = 0; i < 4; ++i) {
        float4 v;
        v.x = c[i][0] + akv[0]; v.y = c[i][1] + akv[1];
        v.z = c[i][2] + akv[2]; v.w = c[i][3] + akv[3];
        *(float4*)&qkBuf[((q0 + ty * 4 + i) * NH + h) * NRES + k0 + tx * 4] = v;
    }
}

// ---------------------------------------------------------------------------
// KS: split-softmax chunk kernel. grid (12 chunks, 768 q), 256 thr.
//   Per block: stage act2d[q, chunk] f32 -> LDS; l2d via MFMA (bf16 cvt on
//   read); logits = qk + l2d + mask, *sqrt(1/3); LOCAL softmax (m,s per h);
//   unnormalized p -> r2d partial (LDS tile) + vv partial (L2-hot vv);
//   write partials + stats.  act2d touches HBM exactly once in the pipeline.
// ---------------------------------------------------------------------------
__global__ __launch_bounds__(256) void kS_split(
    const float* __restrict__ act2d, const float* __restrict__ smask,
    const ushort* __restrict__ w2dT, const float* __restrict__ qkBuf,
    const float* __restrict__ vv, float* __restrict__ part)
{
    const int chunk = blockIdx.x, q = blockIdx.y, tid = threadIdx.x;
    const int k0 = chunk * 64;
    __shared__ float tileF[64 * 132];      // 33.8 KB f32 act2d chunk
    __shared__ float p_lds[16 * 72];       // 4.6 KB unnormalized p[h][k]
    __shared__ float redM[64], redS[64];
    __shared__ float mS[16];
    __shared__ float scrv[960];            // vv kg-combine
    const int lane = tid & 63, wvI = tid >> 6;
    const int nb = lane & 15, quad = lane >> 4;
    const int kb = k0 + wvI * 16 + quad * 4;

    // B-frags (w2d): B[kc=quad*8+j+32s][n=nb]
    bf16x8 bfr[4];
    #pragma unroll
    for (int s = 0; s < 4; ++s)
        bfr[s] = *(const bf16x8*)&w2dT[nb * 128 + quad * 8 + s * 32];

    // stage f32 tile (coalesced)
    const float* src = act2d + ((size_t)q * NRES + k0) * C2V;
    #pragma unroll
    for (int i = 0; i < 8; ++i) {
        int f = tid + i * 256;              // 2048 float4 chunks (64 rows x 32)
        int r = f >> 5, c4 = f & 31;
        *(float4*)&tileF[r * 132 + c4 * 4] = ((const float4*)src)[f];
    }
    // prefetch qk + key-mask (independent global loads)
    float4 qk = {0,0,0,0}, sm = {1.f,1.f,1.f,1.f};
    if (nb < NH) {
        qk = *(const float4*)&qkBuf[((size_t)(q * NH + nb)) * NRES + kb];
        sm = *(const float4*)&smask[kb];
    }
    const float smq = smask[q];
    __syncthreads();

    // MFMA l2d: A-frags from f32 tile, cvt to bf16 in-register
    f32x4 acc = {0.f, 0.f, 0.f, 0.f};
    #pragma unroll
    for (int s = 0; s < 4; ++s) {
        const float* tp = &tileF[(wvI * 16 + nb) * 132 + quad * 8 + s * 32];
        float4 u = *(const float4*)tp;
        float4 w = *(const float4*)(tp + 4);
        bf16x8 af;
        af[0] = (short)f2bf(u.x); af[1] = (short)f2bf(u.y);
        af[2] = (short)f2bf(u.z); af[3] = (short)f2bf(u.w);
        af[4] = (short)f2bf(w.x); af[5] = (short)f2bf(w.y);
        af[6] = (short)f2bf(w.z); af[7] = (short)f2bf(w.w);
        acc = __builtin_amdgcn_mfma_f32_16x16x32_bf16(af, bfr[s], acc, 0, 0, 0);
    }

    float l0 = -3e38f, l1 = -3e38f, l2 = -3e38f, l3 = -3e38f;
    if (nb < NH) {
        const float scale = 0.5773502691896258f;   // sqrt(1/3)
        l0 = (qk.x + acc[0] - 1e5f * (1.f - smq * sm.x)) * scale;
        l1 = (qk.y + acc[1] - 1e5f * (1.f - smq * sm.y)) * scale;
        l2 = (qk.z + acc[2] - 1e5f * (1.f - smq * sm.z)) * scale;
        l3 = (qk.w + acc[3] - 1e5f * (1.f - smq * sm.w)) * scale;
    }
    // local max per head over the 64 chunk keys
    float lmax = fmaxf(fmaxf(l0, l1), fmaxf(l2, l3));
    lmax = fmaxf(lmax, __shfl_xor(lmax, 16, 64));
    lmax = fmaxf(lmax, __shfl_xor(lmax, 32, 64));
    if (quad == 0) redM[nb * 4 + wvI] = lmax;
    __syncthreads();
    if (tid < NH)
        mS[tid] = fmaxf(fmaxf(redM[tid * 4], redM[tid * 4 + 1]),
                        fmaxf(redM[tid * 4 + 2], redM[tid * 4 + 3]));
    __syncthreads();
    // p = exp(l - m_local), chunk sum
    float psum = 0.f;
    if (nb < NH) {
        float mn = mS[nb];
        float e0 = __expf(l0 - mn), e1 = __expf(l1 - mn);
        float e2 = __expf(l2 - mn), e3 = __expf(l3 - mn);
        psum = e0 + e1 + e2 + e3;
        float4 ev = {e0, e1, e2, e3};
        *(float4*)&p_lds[nb * 72 + wvI * 16 + quad * 4] = ev;
    }
    psum += __shfl_xor(psum, 16, 64);
    psum += __shfl_xor(psum, 32, 64);
    if (quad == 0) redS[nb * 4 + wvI] = psum;
    __syncthreads();                                   // p_lds + redS ready

    float* pb = part + (size_t)(q * 12 + chunk) * PSTR;
    if (tid < NH) {
        pb[2016 + tid] = mS[tid];
        pb[2032 + tid] = redS[tid * 4] + redS[tid * 4 + 1]
                       + redS[tid * 4 + 2] + redS[tid * 4 + 3];
    }

    // ---- r2d partial: 384 items (h, c4), each sums 64 k from LDS ----
    for (int item = tid; item < 384; item += 256) {
        const int h = item >> 5, c4 = item & 31;
        const float* pr = &p_lds[h * 72];
        float4 a = {0.f, 0.f, 0.f, 0.f};
        #pragma unroll 4
        for (int k = 0; k < 64; ++k) {
            float p = pr[k];
            float4 t = *(const float4*)&tileF[k * 132 + c4 * 4];
            a.x += p * t.x; a.y += p * t.y; a.z += p * t.z; a.w += p * t.w;
        }
        *(float4*)&pb[h * 128 + c4 * 4] = a;
    }

    // ---- vv partial: j in [0,480), split k into two halves ----
    const int j4 = tid & 127, kg = tid >> 7;
    float4 pv = {0.f, 0.f, 0.f, 0.f};
    if (j4 < 120) {
        const int h = (j4 < 48) ? (j4 >> 2) : ((j4 - 48) / 6);
        const float* pr = &p_lds[h * 72 + kg * 32];
        const float* col = vv + (size_t)(k0 + kg * 32) * VVD + j4 * 4;
        #pragma unroll 4
        for (int k = 0; k < 32; ++k) {
            float p = pr[k];
            float4 t = *(const float4*)(col + (size_t)k * VVD);
            pv.x += p * t.x; pv.y += p * t.y; pv.z += p * t.z; pv.w += p * t.w;
        }
        *(float4*)&scrv[(kg * 120 + j4) * 4] = pv;
    }
    __syncthreads();
    if (tid < 120) {
        float4 a = *(const float4*)&scrv[tid * 4];
        float4 b = *(const float4*)&scrv[(120 + tid) * 4];
        float4 s = {a.x + b.x, a.y + b.y, a.z + b.z, a.w + b.w};
        *(float4*)&pb[1536 + tid * 4] = s;
    }
}

// ---------------------------------------------------------------------------
// KR: per-q flash reduction of the 12 chunk partials + epilogue.
//     Block 0 zeroes the k5 split-K counters.
// ---------------------------------------------------------------------------
__global__ __launch_bounds__(256) void kR_reduce(
    const float* __restrict__ part, const float* __restrict__ rot,
    const float* __restrict__ trans, float* __restrict__ F,
    unsigned* __restrict__ cnt)
{
    const int q = blockIdx.x, tid = threadIdx.x;
    __shared__ float mA[12 * 16], sA[12 * 16], fC[12 * 16];
    __shared__ float il[16];
    __shared__ float scrR[288];
    __shared__ float rotS[9], transS[3];

    if (q == 0 && tid < 72) cnt[tid] = 0u;
    if (tid < 9) rotS[tid] = rot[q * 9 + tid];
    if (tid < 3) transS[tid] = trans[q * 3 + tid];

    const float* pq = part + (size_t)q * 12 * PSTR;
    if (tid < 144) {
        int c = tid % 12, h = tid / 12;
        mA[c * 16 + h] = pq[(size_t)c * PSTR + 2016 + h];
        sA[c * 16 + h] = pq[(size_t)c * PSTR + 2032 + h];
    }
    __syncthreads();
    if (tid < NH) {
        float M = -3e38f;
        #pragma unroll
        for (int c = 0; c < 12; ++c) M = fmaxf(M, mA[c * 16 + tid]);
        float S = 0.f;
        #pragma unroll
        for (int c = 0; c < 12; ++c) {
            float f = __expf(mA[c * 16 + tid] - M);
            fC[c * 16 + tid] = f;
            S += f * sA[c * 16 + tid];
        }
        il[tid] = 1.f / S;
    }
    __syncthreads();

    float* Fq = F + q * FDIM;
    // r2d combine: 1536 outputs
    for (int j = tid; j < 1536; j += 256) {
        const int h = j >> 7;
        float s = 0.f;
        #pragma unroll
        for (int c = 0; c < 12; ++c)
            s += fC[c * 16 + h] * pq[(size_t)c * PSTR + j];
        Fq[576 + j] = s * il[h];
    }
    // vv combine: 120 float4 outputs
    if (tid < 120) {
        const int h = (tid < 48) ? (tid >> 2) : ((tid - 48) / 6);
        float4 s = {0.f, 0.f, 0.f, 0.f};
        #pragma unroll
        for (int c = 0; c < 12; ++c) {
            float f = fC[c * 16 + h];
            float4 v = *(const float4*)&pq[(size_t)c * PSTR + 1536 + tid * 4];
            s.x += f * v.x; s.y += f * v.y; s.z += f * v.z; s.w += f * v.w;
        }
        const float l = il[h];
        s.x *= l; s.y *= l; s.z *= l; s.w *= l;
        if (tid < 48) {
            *(float4*)&Fq[tid * 4] = s;                 // res_scalar (192)
        } else {
            *(float4*)&scrR[(tid - 48) * 4] = s;        // rpg (288)
        }
    }
    __syncthreads();
    if (tid < 96) {
        float gx = scrR[tid * 3]     - transS[0];
        float gy = scrR[tid * 3 + 1] - transS[1];
        float gz = scrR[tid * 3 + 2] - transS[2];
        // invert_apply: rpl_i = sum_j R[j][i] * g_j
        float x = rotS[0] * gx + rotS[3] * gy + rotS[6] * gz;
        float y = rotS[1] * gx + rotS[4] * gy + rotS[7] * gz;
        float z = rotS[2] * gx + rotS[5] * gy + rotS[8] * gz;
        Fq[192 + tid] = x;
        Fq[288 + tid] = y;
        Fq[384 + tid] = z;
        Fq[480 + tid] = sqrtf(x * x + y * y + z * z);
    }
}

// ---------------------------------------------------------------------------
// K5: split-K partials; last block per (m,n) tile reduces + bias -> out.
// ---------------------------------------------------------------------------
__global__ __launch_bounds__(256) void k5_partial(
    const float* __restrict__ F, const float* __restrict__ wfin,
    const float* __restrict__ bfin, float* __restrict__ part,
    unsigned* __restrict__ cnt, float* __restrict__ out)
{
    const int n0 = blockIdx.x * 64, m0 = blockIdx.y * 64, kz = blockIdx.z;
    const int kbeg = kz * 192;
    __shared__ float As[64 * 33];
    __shared__ float Bs[32 * 68];
    const int tid = threadIdx.x, tx = tid & 15, ty = tid >> 4;
    float c[4][4] = {};

    for (int kt = kbeg; kt < kbeg + 192; kt += 32) {
        for (int idx = tid; idx < 64 * 32; idx += 256) {
            int r = idx >> 5, j = idx & 31;
            As[r * 33 + j] = F[(m0 + r) * FDIM + kt + j];
        }
        for (int idx = tid; idx < 32 * 64; idx += 256) {
            int r = idx >> 6, col = idx & 63;
            Bs[r * 68 + col] = wfin[(kt + r) * 384 + n0 + col];
        }
        __syncthreads();
        #pragma unroll
        for (int kk = 0; kk < 32; ++kk) {
            float a[4];
            #pragma unroll
            for (int i = 0; i < 4; ++i) a[i] = As[(ty * 4 + i) * 33 + kk];
            float4 b4 = *(const float4*)&Bs[kk * 68 + tx * 4];
            float b[4] = {b4.x, b4.y, b4.z, b4.w};
            #pragma unroll
            for (int i = 0; i < 4; ++i)
                #pragma unroll
                for (int j = 0; j < 4; ++j) c[i][j] += a[i] * b[j];
        }
        __syncthreads();
    }
    float* dst = part + (size_t)kz * (768 * 384);
    #pragma unroll
    for (int i = 0; i < 4; ++i) {
        float4 v = {c[i][0], c[i][1], c[i][2], c[i][3]};
        *(float4*)&dst[(m0 + ty * 4 + i) * 384 + n0 + tx * 4] = v;
    }

    __threadfence();
    __shared__ int isLast;
    if (tid == 0) {
        unsigned old = atomicAdd(&cnt[blockIdx.y * 6 + blockIdx.x], 1u);
        isLast = (old == KSPLIT - 1) ? 1 : 0;
    }
    __syncthreads();
    if (isLast) {
        __threadfence();
        #pragma unroll
        for (int i = 0; i < 4; ++i) {
            const int row = m0 + ty * 4 + i, colb = n0 + tx * 4;
            float4 s = *(const float4*)&bfin[colb];
            #pragma unroll
            for (int kzz = 0; kzz < KSPLIT; ++kzz) {
                float4 v = *(const float4*)&part[(size_t)kzz * (768 * 384)
                                                 + (size_t)row * 384 + colb];
                s.x += v.x; s.y += v.y; s.z += v.z; s.w += v.w;
            }
            *(float4*)&out[(size_t)row * 384 + colb] = s;
        }
    }
}

// ---------------------------------------------------------------------------
extern "C" void kernel_launch(void* const* d_in, const int* in_sizes, int n_in,
                              void* d_out, int out_size, void* d_ws, size_t ws_size,
                              hipStream_t stream) {
    const float* act   = (const float*)d_in[0];
    const float* act2d = (const float*)d_in[1];
    const float* smask = (const float*)d_in[2];
    const float* rot   = (const float*)d_in[3];
    const float* trans = (const float*)d_in[4];
    const float* wq    = (const float*)d_in[5];
    const float* wk    = (const float*)d_in[6];
    const float* wvv   = (const float*)d_in[7];
    const float* wqp   = (const float*)d_in[8];
    const float* bqp   = (const float*)d_in[9];
    const float* wkp   = (const float*)d_in[10];
    const float* bkp   = (const float*)d_in[11];
    const float* wvp   = (const float*)d_in[12];
    const float* bvp   = (const float*)d_in[13];
    const float* w2d   = (const float*)d_in[14];
    // d_in[15] = b2d: constant over k, cancels in softmax over k -> unused
    const float* wfin  = (const float*)d_in[16];
    const float* bfin  = (const float*)d_in[17];
    const float* tw    = (const float*)d_in[18];

    float* W      = (float*)d_ws;
    float* proj   = W;                       // 768*1152
    float* Qv     = proj   + 768 * NPROJ;    // 768*12*28
    float* Kv     = Qv     + 768 * NH * QKD;
    float* akArr  = Kv     + 768 * NH * QKD; // 768*12
    float* vvA    = akArr  + 768 * NH;       // 768*480
    float* qkBuf  = vvA    + 768 * VVD;      // 768*12*768
    float* F      = qkBuf  + 768 * NH * NRES;// 768*2112
    float* partS  = F      + 768 * FDIM;     // 768*12*2048 (split partials)
    ushort* w2dT  = (ushort*)(partS + 768 * 12 * PSTR); // 2048 bf16
    unsigned* cnt = (unsigned*)(w2dT + 2048);           // 72 counters
    float* part5  = qkBuf;                   // k5 partials alias qkBuf (dead)

    k1_proj<<<dim3(18, 12), 256, 0, stream>>>(act, wq, wk, wvv, wqp, wkp, wvp,
                                              bqp, bkp, bvp, w2d, proj, w2dT);
    k2_prep<<<dim3(NRES), 64, 0, stream>>>(proj, rot, trans, tw, Qv, Kv, akArr, vvA);
    k2b_qk<<<dim3(12, 12, NH), 256, 0, stream>>>(Qv, Kv, akArr, qkBuf);
    kS_split<<<dim3(12, NRES), 256, 0, stream>>>(act2d, smask, w2dT, qkBuf,
                                                 vvA, partS);
    kR_reduce<<<dim3(NRES), 256, 0, stream>>>(partS, rot, trans, F, cnt);
    k5_partial<<<dim3(6, 12, KSPLIT), 256, 0, stream>>>(F, wfin, bfin, part5, cnt,
                                                        (float*)d_out);
}

// Round 6
// 632.148 us; speedup vs baseline: 1.3804x; 1.1443x over previous
//
#include <hip/hip_runtime.h>
#include <math.h>

// Problem constants (B=1)
#define NH    12      // heads
#define NRES  768     // sequence length
#define C1V   384
#define C2V   128
#define NPROJ 1152    // 192+192+192+144+144+288
#define QKD   28      // 16 scalar + 12 point dims
#define FDIM  2112    // 192 + 3*96 + 96 + 1536
#define VVD   480     // 192 (v) + 288 (vp global)
#define KSPLIT 11     // k5 split-K factor (2112 = 11 * 192)
#define PSTR  2048    // per-(q,chunk) partial stride (floats)

typedef __attribute__((ext_vector_type(8))) short bf16x8;
typedef __attribute__((ext_vector_type(4))) float f32x4;

__device__ __forceinline__ float softplusf_(float x) {
    return (x > 20.f) ? x : log1pf(__expf(x));
}
__device__ __forceinline__ ushort f2bf(float x) {   // RNE f32 -> bf16
    union { float f; unsigned u; } v; v.f = x;
    unsigned r = (v.u + 0x7fffu + ((v.u >> 16) & 1u)) >> 16;
    return (ushort)r;
}

// ---------------------------------------------------------------------------
// K1: proj = act @ [wq|wk|wv|wqp|wkp|wvp] + [0|0|0|bqp|bkp|bvp]
//     block(0,0) additionally prepares w2dT (bf16 transposed w2d).
// ---------------------------------------------------------------------------
__global__ __launch_bounds__(256) void k1_proj(
    const float* __restrict__ act,
    const float* __restrict__ wq, const float* __restrict__ wk,
    const float* __restrict__ wv, const float* __restrict__ wqp,
    const float* __restrict__ wkp, const float* __restrict__ wvp,
    const float* __restrict__ bqp, const float* __restrict__ bkp,
    const float* __restrict__ bvp, const float* __restrict__ w2d,
    float* __restrict__ proj, ushort* __restrict__ w2dT)
{
    __shared__ float As[64 * 33];
    __shared__ float Bs[32 * 68];
    const int n0 = blockIdx.x * 64, m0 = blockIdx.y * 64;
    const int tid = threadIdx.x;
    const int tx = tid & 15, ty = tid >> 4;
    float c[4][4] = {};

    for (int kt = 0; kt < C1V; kt += 32) {
        for (int idx = tid; idx < 64 * 32; idx += 256) {
            int r = idx >> 5, j = idx & 31;
            As[r * 33 + j] = act[(m0 + r) * C1V + kt + j];
        }
        for (int idx = tid; idx < 32 * 64; idx += 256) {
            int r = idx >> 6, col = idx & 63;
            int jj = n0 + col, k = kt + r;
            float w;
            if      (jj < 192) w = wq [k * 192 + jj];
            else if (jj < 384) w = wk [k * 192 + jj - 192];
            else if (jj < 576) w = wv [k * 192 + jj - 384];
            else if (jj < 720) w = wqp[k * 144 + jj - 576];
            else if (jj < 864) w = wkp[k * 144 + jj - 720];
            else               w = wvp[k * 288 + jj - 864];
            Bs[r * 68 + col] = w;
        }
        __syncthreads();
        #pragma unroll
        for (int kk = 0; kk < 32; ++kk) {
            float a[4];
            #pragma unroll
            for (int i = 0; i < 4; ++i) a[i] = As[(ty * 4 + i) * 33 + kk];
            float4 b4 = *(const float4*)&Bs[kk * 68 + tx * 4];
            float b[4] = {b4.x, b4.y, b4.z, b4.w};
            #pragma unroll
            for (int i = 0; i < 4; ++i)
                #pragma unroll
                for (int j = 0; j < 4; ++j) c[i][j] += a[i] * b[j];
        }
        __syncthreads();
    }
    float biasv[4];
    #pragma unroll
    for (int j = 0; j < 4; ++j) {
        int col = n0 + tx * 4 + j;
        biasv[j] = (col >= 864) ? bvp[col - 864]
                 : (col >= 720) ? bkp[col - 720]
                 : (col >= 576) ? bqp[col - 576] : 0.f;
    }
    #pragma unroll
    for (int i = 0; i < 4; ++i) {
        float4 v;
        v.x = c[i][0] + biasv[0]; v.y = c[i][1] + biasv[1];
        v.z = c[i][2] + biasv[2]; v.w = c[i][3] + biasv[3];
        *(float4*)&proj[(m0 + ty * 4 + i) * NPROJ + n0 + tx * 4] = v;
    }
    if (n0 == 0 && m0 == 0) {
        for (int idx = tid; idx < 2048; idx += 256) {
            int h = idx >> 7, cc = idx & 127;
            w2dT[idx] = (h < NH) ? f2bf(w2d[cc * NH + h]) : (ushort)0;
        }
    }
}

// ---------------------------------------------------------------------------
// K2: per-residue prep. Qv[n][h][28], Kv[n][h][28], ak[n][h], vv[n][480].
// ---------------------------------------------------------------------------
__global__ __launch_bounds__(64) void k2_prep(
    const float* __restrict__ proj, const float* __restrict__ rot,
    const float* __restrict__ trans, const float* __restrict__ tw,
    float* __restrict__ Qv, float* __restrict__ Kv,
    float* __restrict__ akArr, float* __restrict__ vv)
{
    const int n = blockIdx.x, tid = threadIdx.x;
    __shared__ float kp2[48];
    const float* pr = proj + n * NPROJ;
    float R[9], T[3];
    #pragma unroll
    for (int i = 0; i < 9; ++i) R[i] = rot[n * 9 + i];
    #pragma unroll
    for (int i = 0; i < 3; ++i) T[i] = trans[n * 3 + i];

    for (int idx = tid; idx < 192; idx += 64) {
        int h = idx >> 4, cc = idx & 15;
        Qv[(n * NH + h) * QKD + cc] = pr[idx] * 0.25f;
        Kv[(n * NH + h) * QKD + cc] = pr[192 + idx];
        vv[n * VVD + idx] = pr[384 + idx];
    }
    if (tid < 48) {
        int h = tid >> 2, p = tid & 3;
        float pwh = 0.23570226039551584f * softplusf_(tw[h]);
        float lx = pr[576 + h * 12 + p];
        float ly = pr[576 + h * 12 + 4 + p];
        float lz = pr[576 + h * 12 + 8 + p];
        float gx = R[0] * lx + R[1] * ly + R[2] * lz + T[0];
        float gy = R[3] * lx + R[4] * ly + R[5] * lz + T[1];
        float gz = R[6] * lx + R[7] * ly + R[8] * lz + T[2];
        float* qd = &Qv[(n * NH + h) * QKD + 16];
        qd[p] = pwh * gx; qd[4 + p] = pwh * gy; qd[8 + p] = pwh * gz;
        lx = pr[720 + h * 12 + p];
        ly = pr[720 + h * 12 + 4 + p];
        lz = pr[720 + h * 12 + 8 + p];
        gx = R[0] * lx + R[1] * ly + R[2] * lz + T[0];
        gy = R[3] * lx + R[4] * ly + R[5] * lz + T[1];
        gz = R[6] * lx + R[7] * ly + R[8] * lz + T[2];
        float* kd = &Kv[(n * NH + h) * QKD + 16];
        kd[p] = gx; kd[4 + p] = gy; kd[8 + p] = gz;
        kp2[tid] = gx * gx + gy * gy + gz * gz;
    }
    __syncthreads();
    if (tid < NH) {
        float pwh = 0.23570226039551584f * softplusf_(tw[tid]);
        akArr[n * NH + tid] = -0.5f * pwh *
            (kp2[tid * 4] + kp2[tid * 4 + 1] + kp2[tid * 4 + 2] + kp2[tid * 4 + 3]);
    }
    for (int idx = tid; idx < 96; idx += 64) {
        int h = idx >> 3, p = idx & 7;
        float lx = pr[864 + h * 24 + p];
        float ly = pr[864 + h * 24 + 8 + p];
        float lz = pr[864 + h * 24 + 16 + p];
        float gx = R[0] * lx + R[1] * ly + R[2] * lz + T[0];
        float gy = R[3] * lx + R[4] * ly + R[5] * lz + T[1];
        float gz = R[6] * lx + R[7] * ly + R[8] * lz + T[2];
        float* dst = &vv[n * VVD + 192 + h * 24 + p * 3];
        dst[0] = gx; dst[1] = gy; dst[2] = gz;
    }
}

// ---------------------------------------------------------------------------
// K2b: qkBuf[q][h][k] = Qv[q,h,:].Kv[k,h,:] + ak[k,h]   (raw, unmasked)
// ---------------------------------------------------------------------------
__global__ __launch_bounds__(256) void k2b_qk(
    const float* __restrict__ Qv, const float* __restrict__ Kv,
    const float* __restrict__ akArr, float* __restrict__ qkBuf)
{
    const int h = blockIdx.z;
    const int k0 = blockIdx.x * 64, q0 = blockIdx.y * 64;
    __shared__ float As[64 * 29];
    __shared__ float Bs[64 * 29];
    const int tid = threadIdx.x, tx = tid & 15, ty = tid >> 4;

    for (int idx = tid; idx < 64 * 28; idx += 256) {
        int r = idx / 28, j = idx - r * 28;
        As[r * 29 + j] = Qv[((q0 + r) * NH + h) * QKD + j];
        Bs[r * 29 + j] = Kv[((k0 + r) * NH + h) * QKD + j];
    }
    __syncthreads();
    float c[4][4] = {};
    #pragma unroll
    for (int kk = 0; kk < 28; ++kk) {
        float a[4], b[4];
        #pragma unroll
        for (int i = 0; i < 4; ++i) a[i] = As[(ty * 4 + i) * 29 + kk];
        #pragma unroll
        for (int j = 0; j < 4; ++j) b[j] = Bs[(tx * 4 + j) * 29 + kk];
        #pragma unroll
        for (int i = 0; i < 4; ++i)
            #pragma unroll
            for (int j = 0; j < 4; ++j) c[i][j] += a[i] * b[j];
    }
    float akv[4];
    #pragma unroll
    for (int j = 0; j < 4; ++j) akv[j] = akArr[(k0 + tx * 4 + j) * NH + h];
    #pragma unroll
    for (int i = 0; i < 4; ++i) {
        float4 v;
        v.x = c[i][0] + akv[0]; v.y = c[i][1] + akv[1];
        v.z = c[i][2] + akv[2]; v.w = c[i][3] + akv[3];
        *(float4*)&qkBuf[((q0 + ty * 4 + i) * NH + h) * NRES + k0 + tx * 4] = v;
    }
}

// ---------------------------------------------------------------------------
// KS: split-softmax chunk kernel. grid (12 chunks, 768 q), 256 thr.
//   Per block: stage act2d[q, chunk] f32 -> LDS; l2d via MFMA (bf16 cvt_pk on
//   read); logits = qk + l2d + mask, *sqrt(1/3); LOCAL softmax (m,s per h);
//   unnormalized p -> r2d partial (LDS tile) + vv partial (L2-hot vv);
//   write partials + stats.  act2d touches HBM exactly once in the pipeline.
// ---------------------------------------------------------------------------
__global__ __launch_bounds__(256) void kS_split(
    const float* __restrict__ act2d, const float* __restrict__ smask,
    const ushort* __restrict__ w2dT, const float* __restrict__ qkBuf,
    const float* __restrict__ vv, float* __restrict__ part)
{
    const int chunk = blockIdx.x, q = blockIdx.y, tid = threadIdx.x;
    const int k0 = chunk * 64;
    __shared__ float tileF[64 * 132];      // 33.8 KB f32 act2d chunk
    __shared__ float p_lds[16 * 72];       // 4.6 KB unnormalized p[h][k]
    __shared__ float redM[64], redS[64];
    __shared__ float mS[16];
    __shared__ float scrv[960];            // vv kg-combine
    const int lane = tid & 63, wvI = tid >> 6;
    const int nb = lane & 15, quad = lane >> 4;
    const int kb = k0 + wvI * 16 + quad * 4;

    // B-frags (w2d): B[kc=quad*8+j+32s][n=nb]
    bf16x8 bfr[4];
    #pragma unroll
    for (int s = 0; s < 4; ++s)
        bfr[s] = *(const bf16x8*)&w2dT[nb * 128 + quad * 8 + s * 32];

    // stage f32 tile (coalesced)
    const float* src = act2d + ((size_t)q * NRES + k0) * C2V;
    #pragma unroll
    for (int i = 0; i < 8; ++i) {
        int f = tid + i * 256;              // 2048 float4 chunks (64 rows x 32)
        int r = f >> 5, c4 = f & 31;
        *(float4*)&tileF[r * 132 + c4 * 4] = ((const float4*)src)[f];
    }
    // prefetch qk + key-mask (independent global loads)
    float4 qk = {0,0,0,0}, sm = {1.f,1.f,1.f,1.f};
    if (nb < NH) {
        qk = *(const float4*)&qkBuf[((size_t)(q * NH + nb)) * NRES + kb];
        sm = *(const float4*)&smask[kb];
    }
    const float smq = smask[q];
    __syncthreads();

    // MFMA l2d: A-frags from f32 tile, packed hw cvt to bf16 (RNE)
    f32x4 acc = {0.f, 0.f, 0.f, 0.f};
    #pragma unroll
    for (int s = 0; s < 4; ++s) {
        const float* tp = &tileF[(wvI * 16 + nb) * 132 + quad * 8 + s * 32];
        float4 u = *(const float4*)tp;
        float4 w = *(const float4*)(tp + 4);
        unsigned c0, c1, c2, c3;
        asm("v_cvt_pk_bf16_f32 %0, %1, %2" : "=v"(c0) : "v"(u.x), "v"(u.y));
        asm("v_cvt_pk_bf16_f32 %0, %1, %2" : "=v"(c1) : "v"(u.z), "v"(u.w));
        asm("v_cvt_pk_bf16_f32 %0, %1, %2" : "=v"(c2) : "v"(w.x), "v"(w.y));
        asm("v_cvt_pk_bf16_f32 %0, %1, %2" : "=v"(c3) : "v"(w.z), "v"(w.w));
        union { unsigned u4[4]; bf16x8 v; } cv;
        cv.u4[0] = c0; cv.u4[1] = c1; cv.u4[2] = c2; cv.u4[3] = c3;
        acc = __builtin_amdgcn_mfma_f32_16x16x32_bf16(cv.v, bfr[s], acc, 0, 0, 0);
    }

    float l0 = -3e38f, l1 = -3e38f, l2 = -3e38f, l3 = -3e38f;
    if (nb < NH) {
        const float scale = 0.5773502691896258f;   // sqrt(1/3)
        l0 = (qk.x + acc[0] - 1e5f * (1.f - smq * sm.x)) * scale;
        l1 = (qk.y + acc[1] - 1e5f * (1.f - smq * sm.y)) * scale;
        l2 = (qk.z + acc[2] - 1e5f * (1.f - smq * sm.z)) * scale;
        l3 = (qk.w + acc[3] - 1e5f * (1.f - smq * sm.w)) * scale;
    }
    // local max per head over the 64 chunk keys
    float lmax = fmaxf(fmaxf(l0, l1), fmaxf(l2, l3));
    lmax = fmaxf(lmax, __shfl_xor(lmax, 16, 64));
    lmax = fmaxf(lmax, __shfl_xor(lmax, 32, 64));
    if (quad == 0) redM[nb * 4 + wvI] = lmax;
    __syncthreads();
    if (tid < NH)
        mS[tid] = fmaxf(fmaxf(redM[tid * 4], redM[tid * 4 + 1]),
                        fmaxf(redM[tid * 4 + 2], redM[tid * 4 + 3]));
    __syncthreads();
    // p = exp(l - m_local), chunk sum
    float psum = 0.f;
    if (nb < NH) {
        float mn = mS[nb];
        float e0 = __expf(l0 - mn), e1 = __expf(l1 - mn);
        float e2 = __expf(l2 - mn), e3 = __expf(l3 - mn);
        psum = e0 + e1 + e2 + e3;
        float4 ev = {e0, e1, e2, e3};
        *(float4*)&p_lds[nb * 72 + wvI * 16 + quad * 4] = ev;
    }
    psum += __shfl_xor(psum, 16, 64);
    psum += __shfl_xor(psum, 32, 64);
    if (quad == 0) redS[nb * 4 + wvI] = psum;
    __syncthreads();                                   // p_lds + redS ready

    float* pb = part + (size_t)(q * 12 + chunk) * PSTR;
    if (tid < NH) {
        pb[2016 + tid] = mS[tid];
        pb[2032 + tid] = redS[tid * 4] + redS[tid * 4 + 1]
                       + redS[tid * 4 + 2] + redS[tid * 4 + 3];
    }

    // ---- r2d partial: 384 items (h, c4), each sums 64 k from LDS ----
    for (int item = tid; item < 384; item += 256) {
        const int h = item >> 5, c4 = item & 31;
        const float* pr = &p_lds[h * 72];
        float4 a = {0.f, 0.f, 0.f, 0.f};
        #pragma unroll 4
        for (int k = 0; k < 64; ++k) {
            float p = pr[k];
            float4 t = *(const float4*)&tileF[k * 132 + c4 * 4];
            a.x += p * t.x; a.y += p * t.y; a.z += p * t.z; a.w += p * t.w;
        }
        *(float4*)&pb[h * 128 + c4 * 4] = a;
    }

    // ---- vv partial: j in [0,480), split k into two halves ----
    const int j4 = tid & 127, kg = tid >> 7;
    float4 pv = {0.f, 0.f, 0.f, 0.f};
    if (j4 < 120) {
        const int h = (j4 < 48) ? (j4 >> 2) : ((j4 - 48) / 6);
        const float* pr = &p_lds[h * 72 + kg * 32];
        const float* col = vv + (size_t)(k0 + kg * 32) * VVD + j4 * 4;
        #pragma unroll 4
        for (int k = 0; k < 32; ++k) {
            float p = pr[k];
            float4 t = *(const float4*)(col + (size_t)k * VVD);
            pv.x += p * t.x; pv.y += p * t.y; pv.z += p * t.z; pv.w += p * t.w;
        }
        *(float4*)&scrv[(kg * 120 + j4) * 4] = pv;
    }
    __syncthreads();
    if (tid < 120) {
        float4 a = *(const float4*)&scrv[tid * 4];
        float4 b = *(const float4*)&scrv[(120 + tid) * 4];
        float4 s = {a.x + b.x, a.y + b.y, a.z + b.z, a.w + b.w};
        *(float4*)&pb[1536 + tid * 4] = s;
    }
}

// ---------------------------------------------------------------------------
// KR: per-q flash reduction of the 12 chunk partials + epilogue.
// ---------------------------------------------------------------------------
__global__ __launch_bounds__(256) void kR_reduce(
    const float* __restrict__ part, const float* __restrict__ rot,
    const float* __restrict__ trans, float* __restrict__ F)
{
    const int q = blockIdx.x, tid = threadIdx.x;
    __shared__ float mA[12 * 16], sA[12 * 16], fC[12 * 16];
    __shared__ float il[16];
    __shared__ float scrR[288];
    __shared__ float rotS[9], transS[3];

    if (tid < 9) rotS[tid] = rot[q * 9 + tid];
    if (tid < 3) transS[tid] = trans[q * 3 + tid];

    const float* pq = part + (size_t)q * 12 * PSTR;
    if (tid < 144) {
        int c = tid % 12, h = tid / 12;
        mA[c * 16 + h] = pq[(size_t)c * PSTR + 2016 + h];
        sA[c * 16 + h] = pq[(size_t)c * PSTR + 2032 + h];
    }
    __syncthreads();
    if (tid < NH) {
        float M = -3e38f;
        #pragma unroll
        for (int c = 0; c < 12; ++c) M = fmaxf(M, mA[c * 16 + tid]);
        float S = 0.f;
        #pragma unroll
        for (int c = 0; c < 12; ++c) {
            float f = __expf(mA[c * 16 + tid] - M);
            fC[c * 16 + tid] = f;
            S += f * sA[c * 16 + tid];
        }
        il[tid] = 1.f / S;
    }
    __syncthreads();

    float* Fq = F + q * FDIM;
    // r2d combine: 1536 outputs
    for (int j = tid; j < 1536; j += 256) {
        const int h = j >> 7;
        float s = 0.f;
        #pragma unroll
        for (int c = 0; c < 12; ++c)
            s += fC[c * 16 + h] * pq[(size_t)c * PSTR + j];
        Fq[576 + j] = s * il[h];
    }
    // vv combine: 120 float4 outputs
    if (tid < 120) {
        const int h = (tid < 48) ? (tid >> 2) : ((tid - 48) / 6);
        float4 s = {0.f, 0.f, 0.f, 0.f};
        #pragma unroll
        for (int c = 0; c < 12; ++c) {
            float f = fC[c * 16 + h];
            float4 v = *(const float4*)&pq[(size_t)c * PSTR + 1536 + tid * 4];
            s.x += f * v.x; s.y += f * v.y; s.z += f * v.z; s.w += f * v.w;
        }
        const float l = il[h];
        s.x *= l; s.y *= l; s.z *= l; s.w *= l;
        if (tid < 48) {
            *(float4*)&Fq[tid * 4] = s;                 // res_scalar (192)
        } else {
            *(float4*)&scrR[(tid - 48) * 4] = s;        // rpg (288)
        }
    }
    __syncthreads();
    if (tid < 96) {
        float gx = scrR[tid * 3]     - transS[0];
        float gy = scrR[tid * 3 + 1] - transS[1];
        float gz = scrR[tid * 3 + 2] - transS[2];
        // invert_apply: rpl_i = sum_j R[j][i] * g_j
        float x = rotS[0] * gx + rotS[3] * gy + rotS[6] * gz;
        float y = rotS[1] * gx + rotS[4] * gy + rotS[7] * gz;
        float z = rotS[2] * gx + rotS[5] * gy + rotS[8] * gz;
        Fq[192 + tid] = x;
        Fq[288 + tid] = y;
        Fq[384 + tid] = z;
        Fq[480 + tid] = sqrtf(x * x + y * y + z * z);
    }
}

// ---------------------------------------------------------------------------
// K5: split-K partials + separate reduce (no device-scope fences).
// ---------------------------------------------------------------------------
__global__ __launch_bounds__(256) void k5_partial(
    const float* __restrict__ F, const float* __restrict__ wfin,
    float* __restrict__ part)
{
    const int n0 = blockIdx.x * 64, m0 = blockIdx.y * 64, kz = blockIdx.z;
    const int kbeg = kz * 192;
    __shared__ float As[64 * 33];
    __shared__ float Bs[32 * 68];
    const int tid = threadIdx.x, tx = tid & 15, ty = tid >> 4;
    float c[4][4] = {};

    for (int kt = kbeg; kt < kbeg + 192; kt += 32) {
        for (int idx = tid; idx < 64 * 32; idx += 256) {
            int r = idx >> 5, j = idx & 31;
            As[r * 33 + j] = F[(m0 + r) * FDIM + kt + j];
        }
        for (int idx = tid; idx < 32 * 64; idx += 256) {
            int r = idx >> 6, col = idx & 63;
            Bs[r * 68 + col] = wfin[(kt + r) * 384 + n0 + col];
        }
        __syncthreads();
        #pragma unroll
        for (int kk = 0; kk < 32; ++kk) {
            float a[4];
            #pragma unroll
            for (int i = 0; i < 4; ++i) a[i] = As[(ty * 4 + i) * 33 + kk];
            float4 b4 = *(const float4*)&Bs[kk * 68 + tx * 4];
            float b[4] = {b4.x, b4.y, b4.z, b4.w};
            #pragma unroll
            for (int i = 0; i < 4; ++i)
                #pragma unroll
                for (int j = 0; j < 4; ++j) c[i][j] += a[i] * b[j];
        }
        __syncthreads();
    }
    float* dst = part + (size_t)kz * (768 * 384);
    #pragma unroll
    for (int i = 0; i < 4; ++i) {
        float4 v = {c[i][0], c[i][1], c[i][2], c[i][3]};
        *(float4*)&dst[(m0 + ty * 4 + i) * 384 + n0 + tx * 4] = v;
    }
}

__global__ __launch_bounds__(256) void k5_reduce(
    const float* __restrict__ part, const float* __restrict__ bfin,
    float* __restrict__ out)
{
    const int e = blockIdx.x * 256 + threadIdx.x;      // float4 index, 73728 total
    const float4* p = (const float4*)part;
    float4 b = ((const float4*)bfin)[e % 96];
    float4 s = {b.x, b.y, b.z, b.w};
    #pragma unroll
    for (int kz = 0; kz < KSPLIT; ++kz) {
        float4 v = p[(size_t)kz * 73728 + e];
        s.x += v.x; s.y += v.y; s.z += v.z; s.w += v.w;
    }
    ((float4*)out)[e] = s;
}

// ---------------------------------------------------------------------------
extern "C" void kernel_launch(void* const* d_in, const int* in_sizes, int n_in,
                              void* d_out, int out_size, void* d_ws, size_t ws_size,
                              hipStream_t stream) {
    const float* act   = (const float*)d_in[0];
    const float* act2d = (const float*)d_in[1];
    const float* smask = (const float*)d_in[2];
    const float* rot   = (const float*)d_in[3];
    const float* trans = (const float*)d_in[4];
    const float* wq    = (const float*)d_in[5];
    const float* wk    = (const float*)d_in[6];
    const float* wvv   = (const float*)d_in[7];
    const float* wqp   = (const float*)d_in[8];
    const float* bqp   = (const float*)d_in[9];
    const float* wkp   = (const float*)d_in[10];
    const float* bkp   = (const float*)d_in[11];
    const float* wvp   = (const float*)d_in[12];
    const float* bvp   = (const float*)d_in[13];
    const float* w2d   = (const float*)d_in[14];
    // d_in[15] = b2d: constant over k, cancels in softmax over k -> unused
    const float* wfin  = (const float*)d_in[16];
    const float* bfin  = (const float*)d_in[17];
    const float* tw    = (const float*)d_in[18];

    float* W      = (float*)d_ws;
    float* proj   = W;                       // 768*1152
    float* Qv     = proj   + 768 * NPROJ;    // 768*12*28
    float* Kv     = Qv     + 768 * NH * QKD;
    float* akArr  = Kv     + 768 * NH * QKD; // 768*12
    float* vvA    = akArr  + 768 * NH;       // 768*480
    float* qkBuf  = vvA    + 768 * VVD;      // 768*12*768
    float* F      = qkBuf  + 768 * NH * NRES;// 768*2112
    float* partS  = F      + 768 * FDIM;     // 768*12*2048 (split partials)
    ushort* w2dT  = (ushort*)(partS + 768 * 12 * PSTR); // 2048 bf16
    float* part5  = qkBuf;                   // k5 partials alias qkBuf (dead)

    k1_proj<<<dim3(18, 12), 256, 0, stream>>>(act, wq, wk, wvv, wqp, wkp, wvp,
                                              bqp, bkp, bvp, w2d, proj, w2dT);
    k2_prep<<<dim3(NRES), 64, 0, stream>>>(proj, rot, trans, tw, Qv, Kv, akArr, vvA);
    k2b_qk<<<dim3(12, 12, NH), 256, 0, stream>>>(Qv, Kv, akArr, qkBuf);
    kS_split<<<dim3(12, NRES), 256, 0, stream>>>(act2d, smask, w2dT, qkBuf,
                                                 vvA, partS);
    kR_reduce<<<dim3(NRES), 256, 0, stream>>>(partS, rot, trans, F);
    k5_partial<<<dim3(6, 12, KSPLIT), 256, 0, stream>>>(F, wfin, part5);
    k5_reduce<<<dim3(288), 256, 0, stream>>>(part5, bfin, (float*)d_out);
}

// Round 7
// 624.599 us; speedup vs baseline: 1.3971x; 1.0121x over previous
//
#include <hip/hip_runtime.h>
#include <math.h>

// Problem constants (B=1)
#define NH    12      // heads
#define NRES  768     // sequence length
#define C1V   384
#define C2V   128
#define NPROJ 1152    // 192+192+192+144+144+288
#define QKD   28      // 16 scalar + 12 point dims
#define FDIM  2112    // 192 + 3*96 + 96 + 1536
#define VVD   480     // 192 (v) + 288 (vp global)
#define KSPLIT 11     // k5 split-K factor (2112 = 11 * 192)
#define PSTR  2048    // per-(q,chunk) partial stride (floats)

typedef __attribute__((ext_vector_type(8))) short bf16x8;
typedef __attribute__((ext_vector_type(4))) float f32x4;

__device__ __forceinline__ float softplusf_(float x) {
    return (x > 20.f) ? x : log1pf(__expf(x));
}
__device__ __forceinline__ ushort f2bf(float x) {   // RNE f32 -> bf16
    union { float f; unsigned u; } v; v.f = x;
    unsigned r = (v.u + 0x7fffu + ((v.u >> 16) & 1u)) >> 16;
    return (ushort)r;
}
__device__ __forceinline__ float bf2f(ushort u) {   // bf16 -> f32
    union { unsigned u; float f; } v; v.u = ((unsigned)u) << 16;
    return v.f;
}

// ---------------------------------------------------------------------------
// K1: proj = act @ [wq|wk|wv|wqp|wkp|wvp] + [0|0|0|bqp|bkp|bvp]
//     block(0,0) additionally prepares w2dT (bf16 transposed w2d).
// ---------------------------------------------------------------------------
__global__ __launch_bounds__(256) void k1_proj(
    const float* __restrict__ act,
    const float* __restrict__ wq, const float* __restrict__ wk,
    const float* __restrict__ wv, const float* __restrict__ wqp,
    const float* __restrict__ wkp, const float* __restrict__ wvp,
    const float* __restrict__ bqp, const float* __restrict__ bkp,
    const float* __restrict__ bvp, const float* __restrict__ w2d,
    float* __restrict__ proj, ushort* __restrict__ w2dT)
{
    __shared__ float As[64 * 33];
    __shared__ float Bs[32 * 68];
    const int n0 = blockIdx.x * 64, m0 = blockIdx.y * 64;
    const int tid = threadIdx.x;
    const int tx = tid & 15, ty = tid >> 4;
    float c[4][4] = {};

    for (int kt = 0; kt < C1V; kt += 32) {
        for (int idx = tid; idx < 64 * 32; idx += 256) {
            int r = idx >> 5, j = idx & 31;
            As[r * 33 + j] = act[(m0 + r) * C1V + kt + j];
        }
        for (int idx = tid; idx < 32 * 64; idx += 256) {
            int r = idx >> 6, col = idx & 63;
            int jj = n0 + col, k = kt + r;
            float w;
            if      (jj < 192) w = wq [k * 192 + jj];
            else if (jj < 384) w = wk [k * 192 + jj - 192];
            else if (jj < 576) w = wv [k * 192 + jj - 384];
            else if (jj < 720) w = wqp[k * 144 + jj - 576];
            else if (jj < 864) w = wkp[k * 144 + jj - 720];
            else               w = wvp[k * 288 + jj - 864];
            Bs[r * 68 + col] = w;
        }
        __syncthreads();
        #pragma unroll
        for (int kk = 0; kk < 32; ++kk) {
            float a[4];
            #pragma unroll
            for (int i = 0; i < 4; ++i) a[i] = As[(ty * 4 + i) * 33 + kk];
            float4 b4 = *(const float4*)&Bs[kk * 68 + tx * 4];
            float b[4] = {b4.x, b4.y, b4.z, b4.w};
            #pragma unroll
            for (int i = 0; i < 4; ++i)
                #pragma unroll
                for (int j = 0; j < 4; ++j) c[i][j] += a[i] * b[j];
        }
        __syncthreads();
    }
    float biasv[4];
    #pragma unroll
    for (int j = 0; j < 4; ++j) {
        int col = n0 + tx * 4 + j;
        biasv[j] = (col >= 864) ? bvp[col - 864]
                 : (col >= 720) ? bkp[col - 720]
                 : (col >= 576) ? bqp[col - 576] : 0.f;
    }
    #pragma unroll
    for (int i = 0; i < 4; ++i) {
        float4 v;
        v.x = c[i][0] + biasv[0]; v.y = c[i][1] + biasv[1];
        v.z = c[i][2] + biasv[2]; v.w = c[i][3] + biasv[3];
        *(float4*)&proj[(m0 + ty * 4 + i) * NPROJ + n0 + tx * 4] = v;
    }
    if (n0 == 0 && m0 == 0) {
        for (int idx = tid; idx < 2048; idx += 256) {
            int h = idx >> 7, cc = idx & 127;
            w2dT[idx] = (h < NH) ? f2bf(w2d[cc * NH + h]) : (ushort)0;
        }
    }
}

// ---------------------------------------------------------------------------
// K2: per-residue prep. Qv[n][h][28], Kv[n][h][28], ak[n][h], vv[n][480]
//     (+ bf16 copy vvB for the kS vv pass).
// ---------------------------------------------------------------------------
__global__ __launch_bounds__(64) void k2_prep(
    const float* __restrict__ proj, const float* __restrict__ rot,
    const float* __restrict__ trans, const float* __restrict__ tw,
    float* __restrict__ Qv, float* __restrict__ Kv,
    float* __restrict__ akArr, float* __restrict__ vv,
    ushort* __restrict__ vvB)
{
    const int n = blockIdx.x, tid = threadIdx.x;
    __shared__ float kp2[48];
    const float* pr = proj + n * NPROJ;
    float R[9], T[3];
    #pragma unroll
    for (int i = 0; i < 9; ++i) R[i] = rot[n * 9 + i];
    #pragma unroll
    for (int i = 0; i < 3; ++i) T[i] = trans[n * 3 + i];

    for (int idx = tid; idx < 192; idx += 64) {
        int h = idx >> 4, cc = idx & 15;
        Qv[(n * NH + h) * QKD + cc] = pr[idx] * 0.25f;
        Kv[(n * NH + h) * QKD + cc] = pr[192 + idx];
        float v = pr[384 + idx];
        vv[n * VVD + idx] = v;
        vvB[n * VVD + idx] = f2bf(v);
    }
    if (tid < 48) {
        int h = tid >> 2, p = tid & 3;
        float pwh = 0.23570226039551584f * softplusf_(tw[h]);
        float lx = pr[576 + h * 12 + p];
        float ly = pr[576 + h * 12 + 4 + p];
        float lz = pr[576 + h * 12 + 8 + p];
        float gx = R[0] * lx + R[1] * ly + R[2] * lz + T[0];
        float gy = R[3] * lx + R[4] * ly + R[5] * lz + T[1];
        float gz = R[6] * lx + R[7] * ly + R[8] * lz + T[2];
        float* qd = &Qv[(n * NH + h) * QKD + 16];
        qd[p] = pwh * gx; qd[4 + p] = pwh * gy; qd[8 + p] = pwh * gz;
        lx = pr[720 + h * 12 + p];
        ly = pr[720 + h * 12 + 4 + p];
        lz = pr[720 + h * 12 + 8 + p];
        gx = R[0] * lx + R[1] * ly + R[2] * lz + T[0];
        gy = R[3] * lx + R[4] * ly + R[5] * lz + T[1];
        gz = R[6] * lx + R[7] * ly + R[8] * lz + T[2];
        float* kd = &Kv[(n * NH + h) * QKD + 16];
        kd[p] = gx; kd[4 + p] = gy; kd[8 + p] = gz;
        kp2[tid] = gx * gx + gy * gy + gz * gz;
    }
    __syncthreads();
    if (tid < NH) {
        float pwh = 0.23570226039551584f * softplusf_(tw[tid]);
        akArr[n * NH + tid] = -0.5f * pwh *
            (kp2[tid * 4] + kp2[tid * 4 + 1] + kp2[tid * 4 + 2] + kp2[tid * 4 + 3]);
    }
    for (int idx = tid; idx < 96; idx += 64) {
        int h = idx >> 3, p = idx & 7;
        float lx = pr[864 + h * 24 + p];
        float ly = pr[864 + h * 24 + 8 + p];
        float lz = pr[864 + h * 24 + 16 + p];
        float gx = R[0] * lx + R[1] * ly + R[2] * lz + T[0];
        float gy = R[3] * lx + R[4] * ly + R[5] * lz + T[1];
        float gz = R[6] * lx + R[7] * ly + R[8] * lz + T[2];
        const int o = n * VVD + 192 + h * 24 + p * 3;
        vv[o] = gx; vv[o + 1] = gy; vv[o + 2] = gz;
        vvB[o] = f2bf(gx); vvB[o + 1] = f2bf(gy); vvB[o + 2] = f2bf(gz);
    }
}

// ---------------------------------------------------------------------------
// K2b: qkBuf[q][h][k] = Qv[q,h,:].Kv[k,h,:] + ak[k,h]   (raw, unmasked)
// ---------------------------------------------------------------------------
__global__ __launch_bounds__(256) void k2b_qk(
    const float* __restrict__ Qv, const float* __restrict__ Kv,
    const float* __restrict__ akArr, float* __restrict__ qkBuf)
{
    const int h = blockIdx.z;
    const int k0 = blockIdx.x * 64, q0 = blockIdx.y * 64;
    __shared__ float As[64 * 29];
    __shared__ float Bs[64 * 29];
    const int tid = threadIdx.x, tx = tid & 15, ty = tid >> 4;

    for (int idx = tid; idx < 64 * 28; idx += 256) {
        int r = idx / 28, j = idx - r * 28;
        As[r * 29 + j] = Qv[((q0 + r) * NH + h) * QKD + j];
        Bs[r * 29 + j] = Kv[((k0 + r) * NH + h) * QKD + j];
    }
    __syncthreads();
    float c[4][4] = {};
    #pragma unroll
    for (int kk = 0; kk < 28; ++kk) {
        float a[4], b[4];
        #pragma unroll
        for (int i = 0; i < 4; ++i) a[i] = As[(ty * 4 + i) * 29 + kk];
        #pragma unroll
        for (int j = 0; j < 4; ++j) b[j] = Bs[(tx * 4 + j) * 29 + kk];
        #pragma unroll
        for (int i = 0; i < 4; ++i)
            #pragma unroll
            for (int j = 0; j < 4; ++j) c[i][j] += a[i] * b[j];
    }
    float akv[4];
    #pragma unroll
    for (int j = 0; j < 4; ++j) akv[j] = akArr[(k0 + tx * 4 + j) * NH + h];
    #pragma unroll
    for (int i = 0; i < 4; ++i) {
        float4 v;
        v.x = c[i][0] + akv[0]; v.y = c[i][1] + akv[1];
        v.z = c[i][2] + akv[2]; v.w = c[i][3] + akv[3];
        *(float4*)&qkBuf[((q0 + ty * 4 + i) * NH + h) * NRES + k0 + tx * 4] = v;
    }
}

// ---------------------------------------------------------------------------
// KS: split-softmax chunk kernel. grid (12 chunks, 768 q), 256 thr.
//   Tile staged as bf16 (R0 kA pattern) -> LDS ~26 KB -> ~6 blocks/CU.
//   l2d MFMA reads fragments directly (no cvt in loop); r2d reads bf16 tile;
//   vv pass reads bf16 vvB (half the L2 bytes).
// ---------------------------------------------------------------------------
__global__ __launch_bounds__(256) void kS_split(
    const float* __restrict__ act2d, const float* __restrict__ smask,
    const ushort* __restrict__ w2dT, const float* __restrict__ qkBuf,
    const ushort* __restrict__ vvB, float* __restrict__ part)
{
    const int chunk = blockIdx.x, q = blockIdx.y, tid = threadIdx.x;
    const int k0 = chunk * 64;
    __shared__ ushort tile[64 * 136];      // 17.4 KB bf16 act2d chunk
    __shared__ float p_lds[16 * 72];       // 4.6 KB unnormalized p[h][k]
    __shared__ float redM[64], redS[64];
    __shared__ float mS[16];
    __shared__ float scrv[960];            // vv kg-combine
    const int lane = tid & 63, wvI = tid >> 6;
    const int nb = lane & 15, quad = lane >> 4;
    const int kb = k0 + wvI * 16 + quad * 4;

    // B-frags (w2d): B[kc=quad*8+j+32s][n=nb]
    bf16x8 bfr[4];
    #pragma unroll
    for (int s = 0; s < 4; ++s)
        bfr[s] = *(const bf16x8*)&w2dT[nb * 128 + quad * 8 + s * 32];

    // stage bf16 tile (proven R0 kA pattern)
    const float* src = act2d + ((size_t)q * NRES + k0) * C2V;
    #pragma unroll
    for (int i = 0; i < 8; ++i) {
        int f = tid + i * 256;              // 2048 float4 chunks (64 rows x 32)
        int r = f >> 5, c4 = f & 31;
        float4 v = ((const float4*)src)[f];
        ushort4 o = { f2bf(v.x), f2bf(v.y), f2bf(v.z), f2bf(v.w) };
        *(ushort4*)&tile[r * 136 + c4 * 4] = o;
    }
    // prefetch qk + key-mask (independent global loads)
    float4 qk = {0,0,0,0}, sm = {1.f,1.f,1.f,1.f};
    if (nb < NH) {
        qk = *(const float4*)&qkBuf[((size_t)(q * NH + nb)) * NRES + kb];
        sm = *(const float4*)&smask[kb];
    }
    const float smq = smask[q];
    __syncthreads();

    // MFMA l2d: direct bf16 fragment reads
    f32x4 acc = {0.f, 0.f, 0.f, 0.f};
    #pragma unroll
    for (int s = 0; s < 4; ++s) {
        bf16x8 af = *(const bf16x8*)&tile[(wvI * 16 + nb) * 136 + quad * 8 + s * 32];
        acc = __builtin_amdgcn_mfma_f32_16x16x32_bf16(af, bfr[s], acc, 0, 0, 0);
    }

    float l0 = -3e38f, l1 = -3e38f, l2 = -3e38f, l3 = -3e38f;
    if (nb < NH) {
        const float scale = 0.5773502691896258f;   // sqrt(1/3)
        l0 = (qk.x + acc[0] - 1e5f * (1.f - smq * sm.x)) * scale;
        l1 = (qk.y + acc[1] - 1e5f * (1.f - smq * sm.y)) * scale;
        l2 = (qk.z + acc[2] - 1e5f * (1.f - smq * sm.z)) * scale;
        l3 = (qk.w + acc[3] - 1e5f * (1.f - smq * sm.w)) * scale;
    }
    // local max per head over the 64 chunk keys
    float lmax = fmaxf(fmaxf(l0, l1), fmaxf(l2, l3));
    lmax = fmaxf(lmax, __shfl_xor(lmax, 16, 64));
    lmax = fmaxf(lmax, __shfl_xor(lmax, 32, 64));
    if (quad == 0) redM[nb * 4 + wvI] = lmax;
    __syncthreads();
    if (tid < NH)
        mS[tid] = fmaxf(fmaxf(redM[tid * 4], redM[tid * 4 + 1]),
                        fmaxf(redM[tid * 4 + 2], redM[tid * 4 + 3]));
    __syncthreads();
    // p = exp(l - m_local), chunk sum
    float psum = 0.f;
    if (nb < NH) {
        float mn = mS[nb];
        float e0 = __expf(l0 - mn), e1 = __expf(l1 - mn);
        float e2 = __expf(l2 - mn), e3 = __expf(l3 - mn);
        psum = e0 + e1 + e2 + e3;
        float4 ev = {e0, e1, e2, e3};
        *(float4*)&p_lds[nb * 72 + wvI * 16 + quad * 4] = ev;
    }
    psum += __shfl_xor(psum, 16, 64);
    psum += __shfl_xor(psum, 32, 64);
    if (quad == 0) redS[nb * 4 + wvI] = psum;
    __syncthreads();                                   // p_lds + redS ready

    float* pb = part + (size_t)(q * 12 + chunk) * PSTR;
    if (tid < NH) {
        pb[2016 + tid] = mS[tid];
        pb[2032 + tid] = redS[tid * 4] + redS[tid * 4 + 1]
                       + redS[tid * 4 + 2] + redS[tid * 4 + 3];
    }

    // ---- r2d partial: 384 items (h, c4), each sums 64 k from bf16 tile ----
    for (int item = tid; item < 384; item += 256) {
        const int h = item >> 5, c4 = item & 31;
        const float* pr = &p_lds[h * 72];
        float4 a = {0.f, 0.f, 0.f, 0.f};
        #pragma unroll 4
        for (int k = 0; k < 64; ++k) {
            float p = pr[k];
            ushort4 t = *(const ushort4*)&tile[k * 136 + c4 * 4];
            a.x += p * bf2f(t.x); a.y += p * bf2f(t.y);
            a.z += p * bf2f(t.z); a.w += p * bf2f(t.w);
        }
        *(float4*)&pb[h * 128 + c4 * 4] = a;
    }

    // ---- vv partial: j in [0,480), split k into two halves, bf16 reads ----
    const int j4 = tid & 127, kg = tid >> 7;
    float4 pv = {0.f, 0.f, 0.f, 0.f};
    if (j4 < 120) {
        const int h = (j4 < 48) ? (j4 >> 2) : ((j4 - 48) / 6);
        const float* pr = &p_lds[h * 72 + kg * 32];
        const ushort* col = vvB + (size_t)(k0 + kg * 32) * VVD + j4 * 4;
        #pragma unroll 4
        for (int k = 0; k < 32; ++k) {
            float p = pr[k];
            ushort4 t = *(const ushort4*)(col + (size_t)k * VVD);
            pv.x += p * bf2f(t.x); pv.y += p * bf2f(t.y);
            pv.z += p * bf2f(t.z); pv.w += p * bf2f(t.w);
        }
        *(float4*)&scrv[(kg * 120 + j4) * 4] = pv;
    }
    __syncthreads();
    if (tid < 120) {
        float4 a = *(const float4*)&scrv[tid * 4];
        float4 b = *(const float4*)&scrv[(120 + tid) * 4];
        float4 s = {a.x + b.x, a.y + b.y, a.z + b.z, a.w + b.w};
        *(float4*)&pb[1536 + tid * 4] = s;
    }
}

// ---------------------------------------------------------------------------
// KR: per-q flash reduction of the 12 chunk partials + epilogue.
// ---------------------------------------------------------------------------
__global__ __launch_bounds__(256) void kR_reduce(
    const float* __restrict__ part, const float* __restrict__ rot,
    const float* __restrict__ trans, float* __restrict__ F)
{
    const int q = blockIdx.x, tid = threadIdx.x;
    __shared__ float mA[12 * 16], sA[12 * 16], fC[12 * 16];
    __shared__ float il[16];
    __shared__ float scrR[288];
    __shared__ float rotS[9], transS[3];

    if (tid < 9) rotS[tid] = rot[q * 9 + tid];
    if (tid < 3) transS[tid] = trans[q * 3 + tid];

    const float* pq = part + (size_t)q * 12 * PSTR;
    if (tid < 144) {
        int c = tid % 12, h = tid / 12;
        mA[c * 16 + h] = pq[(size_t)c * PSTR + 2016 + h];
        sA[c * 16 + h] = pq[(size_t)c * PSTR + 2032 + h];
    }
    __syncthreads();
    if (tid < NH) {
        float M = -3e38f;
        #pragma unroll
        for (int c = 0; c < 12; ++c) M = fmaxf(M, mA[c * 16 + tid]);
        float S = 0.f;
        #pragma unroll
        for (int c = 0; c < 12; ++c) {
            float f = __expf(mA[c * 16 + tid] - M);
            fC[c * 16 + tid] = f;
            S += f * sA[c * 16 + tid];
        }
        il[tid] = 1.f / S;
    }
    __syncthreads();

    float* Fq = F + q * FDIM;
    // r2d combine: 1536 outputs
    for (int j = tid; j < 1536; j += 256) {
        const int h = j >> 7;
        float s = 0.f;
        #pragma unroll
        for (int c = 0; c < 12; ++c)
            s += fC[c * 16 + h] * pq[(size_t)c * PSTR + j];
        Fq[576 + j] = s * il[h];
    }
    // vv combine: 120 float4 outputs
    if (tid < 120) {
        const int h = (tid < 48) ? (tid >> 2) : ((tid - 48) / 6);
        float4 s = {0.f, 0.f, 0.f, 0.f};
        #pragma unroll
        for (int c = 0; c < 12; ++c) {
            float f = fC[c * 16 + h];
            float4 v = *(const float4*)&pq[(size_t)c * PSTR + 1536 + tid * 4];
            s.x += f * v.x; s.y += f * v.y; s.z += f * v.z; s.w += f * v.w;
        }
        const float l = il[h];
        s.x *= l; s.y *= l; s.z *= l; s.w *= l;
        if (tid < 48) {
            *(float4*)&Fq[tid * 4] = s;                 // res_scalar (192)
        } else {
            *(float4*)&scrR[(tid - 48) * 4] = s;        // rpg (288)
        }
    }
    __syncthreads();
    if (tid < 96) {
        float gx = scrR[tid * 3]     - transS[0];
        float gy = scrR[tid * 3 + 1] - transS[1];
        float gz = scrR[tid * 3 + 2] - transS[2];
        // invert_apply: rpl_i = sum_j R[j][i] * g_j
        float x = rotS[0] * gx + rotS[3] * gy + rotS[6] * gz;
        float y = rotS[1] * gx + rotS[4] * gy + rotS[7] * gz;
        float z = rotS[2] * gx + rotS[5] * gy + rotS[8] * gz;
        Fq[192 + tid] = x;
        Fq[288 + tid] = y;
        Fq[384 + tid] = z;
        Fq[480 + tid] = sqrtf(x * x + y * y + z * z);
    }
}

// ---------------------------------------------------------------------------
// K5: split-K partials + separate reduce (no device-scope fences).
// ---------------------------------------------------------------------------
__global__ __launch_bounds__(256) void k5_partial(
    const float* __restrict__ F, const float* __restrict__ wfin,
    float* __restrict__ part)
{
    const int n0 = blockIdx.x * 64, m0 = blockIdx.y * 64, kz = blockIdx.z;
    const int kbeg = kz * 192;
    __shared__ float As[64 * 33];
    __shared__ float Bs[32 * 68];
    const int tid = threadIdx.x, tx = tid & 15, ty = tid >> 4;
    float c[4][4] = {};

    for (int kt = kbeg; kt < kbeg + 192; kt += 32) {
        for (int idx = tid; idx < 64 * 32; idx += 256) {
            int r = idx >> 5, j = idx & 31;
            As[r * 33 + j] = F[(m0 + r) * FDIM + kt + j];
        }
        for (int idx = tid; idx < 32 * 64; idx += 256) {
            int r = idx >> 6, col = idx & 63;
            Bs[r * 68 + col] = wfin[(kt + r) * 384 + n0 + col];
        }
        __syncthreads();
        #pragma unroll
        for (int kk = 0; kk < 32; ++kk) {
            float a[4];
            #pragma unroll
            for (int i = 0; i < 4; ++i) a[i] = As[(ty * 4 + i) * 33 + kk];
            float4 b4 = *(const float4*)&Bs[kk * 68 + tx * 4];
            float b[4] = {b4.x, b4.y, b4.z, b4.w};
            #pragma unroll
            for (int i = 0; i < 4; ++i)
                #pragma unroll
                for (int j = 0; j < 4; ++j) c[i][j] += a[i] * b[j];
        }
        __syncthreads();
    }
    float* dst = part + (size_t)kz * (768 * 384);
    #pragma unroll
    for (int i = 0; i < 4; ++i) {
        float4 v = {c[i][0], c[i][1], c[i][2], c[i][3]};
        *(float4*)&dst[(m0 + ty * 4 + i) * 384 + n0 + tx * 4] = v;
    }
}

__global__ __launch_bounds__(256) void k5_reduce(
    const float* __restrict__ part, const float* __restrict__ bfin,
    float* __restrict__ out)
{
    const int e = blockIdx.x * 256 + threadIdx.x;      // float4 index, 73728 total
    const float4* p = (const float4*)part;
    float4 b = ((const float4*)bfin)[e % 96];
    float4 s = {b.x, b.y, b.z, b.w};
    #pragma unroll
    for (int kz = 0; kz < KSPLIT; ++kz) {
        float4 v = p[(size_t)kz * 73728 + e];
        s.x += v.x; s.y += v.y; s.z += v.z; s.w += v.w;
    }
    ((float4*)out)[e] = s;
}

// ---------------------------------------------------------------------------
extern "C" void kernel_launch(void* const* d_in, const int* in_sizes, int n_in,
                              void* d_out, int out_size, void* d_ws, size_t ws_size,
                              hipStream_t stream) {
    const float* act   = (const float*)d_in[0];
    const float* act2d = (const float*)d_in[1];
    const float* smask = (const float*)d_in[2];
    const float* rot   = (const float*)d_in[3];
    const float* trans = (const float*)d_in[4];
    const float* wq    = (const float*)d_in[5];
    const float* wk    = (const float*)d_in[6];
    const float* wvv   = (const float*)d_in[7];
    const float* wqp   = (const float*)d_in[8];
    const float* bqp   = (const float*)d_in[9];
    const float* wkp   = (const float*)d_in[10];
    const float* bkp   = (const float*)d_in[11];
    const float* wvp   = (const float*)d_in[12];
    const float* bvp   = (const float*)d_in[13];
    const float* w2d   = (const float*)d_in[14];
    // d_in[15] = b2d: constant over k, cancels in softmax over k -> unused
    const float* wfin  = (const float*)d_in[16];
    const float* bfin  = (const float*)d_in[17];
    const float* tw    = (const float*)d_in[18];

    float* W      = (float*)d_ws;
    float* proj   = W;                       // 768*1152
    float* Qv     = proj   + 768 * NPROJ;    // 768*12*28
    float* Kv     = Qv     + 768 * NH * QKD;
    float* akArr  = Kv     + 768 * NH * QKD; // 768*12
    float* vvA    = akArr  + 768 * NH;       // 768*480
    float* qkBuf  = vvA    + 768 * VVD;      // 768*12*768
    float* F      = qkBuf  + 768 * NH * NRES;// 768*2112
    float* partS  = F      + 768 * FDIM;     // 768*12*2048 (split partials)
    ushort* w2dT  = (ushort*)(partS + 768 * 12 * PSTR); // 2048 bf16
    ushort* vvB   = w2dT + 2048;             // 768*480 bf16
    float* part5  = qkBuf;                   // k5 partials alias qkBuf (dead)

    k1_proj<<<dim3(18, 12), 256, 0, stream>>>(act, wq, wk, wvv, wqp, wkp, wvp,
                                              bqp, bkp, bvp, w2d, proj, w2dT);
    k2_prep<<<dim3(NRES), 64, 0, stream>>>(proj, rot, trans, tw, Qv, Kv, akArr,
                                           vvA, vvB);
    k2b_qk<<<dim3(12, 12, NH), 256, 0, stream>>>(Qv, Kv, akArr, qkBuf);
    kS_split<<<dim3(12, NRES), 256, 0, stream>>>(act2d, smask, w2dT, qkBuf,
                                                 vvB, partS);
    kR_reduce<<<dim3(NRES), 256, 0, stream>>>(partS, rot, trans, F);
    k5_partial<<<dim3(6, 12, KSPLIT), 256, 0, stream>>>(F, wfin, part5);
    k5_reduce<<<dim3(288), 256, 0, stream>>>(part5, bfin, (float*)d_out);
}